// Round 1
// baseline (315.530 us; speedup 1.0000x reference)
//
#include <hip/hip_runtime.h>

// Problem constants
constexpr int Bn   = 4;
constexpr int Tn   = 2048;
constexpr int TPn  = 256;
constexpr int TALLn = 2304;   // TPn + Tn
constexpr int Cn   = 768;
constexpr int Hn   = 12;
constexpr int HDn  = 64;

typedef __bf16 bf16x8 __attribute__((ext_vector_type(8)));
typedef float  f32x4  __attribute__((ext_vector_type(4)));

// RNE float -> bf16 bits (finite inputs only)
__device__ __forceinline__ unsigned short f2bf(float f) {
    unsigned int x = __float_as_uint(f);
    x += 0x7fffu + ((x >> 16) & 1u);
    return (unsigned short)(x >> 16);
}

// async global->LDS, 16B per lane; lds dst must be wave-uniform base (HW appends lane*16)
#define ASYNC16(gsrc, ldst)                                                           \
    __builtin_amdgcn_global_load_lds((__attribute__((address_space(1))) void*)(gsrc), \
                                     (__attribute__((address_space(3))) void*)(ldst), \
                                     16, 0, 0)

// ---------------- cast kernels ----------------
__global__ __launch_bounds__(256) void k_build_xfull(
        const float* __restrict__ x, const float* __restrict__ pre,
        unsigned short* __restrict__ xf) {
    int idx = blockIdx.x * 256 + threadIdx.x;           // one float4 per thread
    int row = idx / (Cn / 4);                           // token row in (B*TALL)
    int c   = (idx - row * (Cn / 4)) * 4;
    int b = row / TALLn, tt = row - b * TALLn;
    const float* src = (tt < TPn) ? pre + ((size_t)b * TPn + tt) * Cn + c
                                  : x   + ((size_t)b * Tn + (tt - TPn)) * Cn + c;
    float4 f = *reinterpret_cast<const float4*>(src);
    ushort4 o = { f2bf(f.x), f2bf(f.y), f2bf(f.z), f2bf(f.w) };
    *reinterpret_cast<ushort4*>(xf + (size_t)row * Cn + c) = o;
}

__global__ __launch_bounds__(256) void k_cast(
        const float* __restrict__ in, unsigned short* __restrict__ out) {
    int idx = (blockIdx.x * 256 + threadIdx.x) * 4;
    float4 f = *reinterpret_cast<const float4*>(in + idx);
    ushort4 o = { f2bf(f.x), f2bf(f.y), f2bf(f.z), f2bf(f.w) };
    *reinterpret_cast<ushort4*>(out + idx) = o;
}

// ---------------- QKV GEMM: (9216 x 768) @ (2304 x 768)^T ----------------
// 128x128 tile, BK=32, 4 waves (2x2), each wave 64x64 via 4x4 16x16x32 MFMAs.
// LDS swizzle: 8-elt chunk of row r stored at slot (chunk ^ ((r>>1)&3)).
__global__ __launch_bounds__(256) void k_qkv_gemm(
        const unsigned short* __restrict__ A, const unsigned short* __restrict__ W,
        unsigned short* __restrict__ Qb, unsigned short* __restrict__ Kb,
        unsigned short* __restrict__ Vt) {
    __shared__ __align__(16) unsigned short As[128 * 32];
    __shared__ __align__(16) unsigned short Bs[128 * 32];
    const int tid  = threadIdx.x;
    const int wave = tid >> 6;
    const int lane = tid & 63;
    const int g = lane >> 4, l16 = lane & 15;
    const int m0 = blockIdx.x * 128, n0 = blockIdx.y * 128;
    const int wr = wave >> 1, wc = wave & 1;

    f32x4 acc[4][4] = {};

    for (int k0 = 0; k0 < Cn; k0 += 32) {
        #pragma unroll
        for (int inst = 0; inst < 2; ++inst) {
            const int li = inst * 256 + tid;            // [0,512)
            const int row = li >> 2, slot = li & 3;
            const int chunk = slot ^ ((row >> 1) & 3);  // inverse-swizzled source
            unsigned short* ldsA = &As[(inst * 256 + wave * 64) * 8];
            unsigned short* ldsB = &Bs[(inst * 256 + wave * 64) * 8];
            ASYNC16(A + (size_t)(m0 + row) * Cn + k0 + chunk * 8, ldsA);
            ASYNC16(W + (size_t)(n0 + row) * Cn + k0 + chunk * 8, ldsB);
        }
        __syncthreads();
        bf16x8 af[4], bfv[4];
        #pragma unroll
        for (int mt = 0; mt < 4; ++mt) {
            const int row = wr * 64 + mt * 16 + l16;
            const int slot = g ^ ((row >> 1) & 3);
            af[mt] = *reinterpret_cast<const bf16x8*>(&As[row * 32 + slot * 8]);
        }
        #pragma unroll
        for (int nt = 0; nt < 4; ++nt) {
            const int row = wc * 64 + nt * 16 + l16;
            const int slot = g ^ ((row >> 1) & 3);
            bfv[nt] = *reinterpret_cast<const bf16x8*>(&Bs[row * 32 + slot * 8]);
        }
        #pragma unroll
        for (int mt = 0; mt < 4; ++mt)
            #pragma unroll
            for (int nt = 0; nt < 4; ++nt)
                acc[mt][nt] = __builtin_amdgcn_mfma_f32_16x16x32_bf16(
                        af[mt], bfv[nt], acc[mt][nt], 0, 0, 0);
        __syncthreads();
    }

    // epilogue: scatter to Q (b,h,t,d), K (b,h,t,d), V^T (b,h,d,t)
    const int b   = m0 / TALLn;        // 2304 % 128 == 0: tile within one batch
    const int t0  = m0 - b * TALLn;
    const int sel = n0 / Cn;           // 768 % 128 == 0: tile within one of q/k/v
    const int hn0 = n0 - sel * Cn;
    #pragma unroll
    for (int mt = 0; mt < 4; ++mt)
        #pragma unroll
        for (int nt = 0; nt < 4; ++nt)
            #pragma unroll
            for (int r = 0; r < 4; ++r) {
                const int t  = t0 + wr * 64 + mt * 16 + g * 4 + r;   // C/D row
                const int hn = hn0 + wc * 64 + nt * 16 + l16;        // C/D col
                const int h = hn >> 6, d = hn & 63;
                const unsigned short v = f2bf(acc[mt][nt][r]);
                if (sel == 0)
                    Qb[(((size_t)b * Hn + h) * TALLn + t) * HDn + d] = v;
                else if (sel == 1)
                    Kb[(((size_t)b * Hn + h) * TALLn + t) * HDn + d] = v;
                else
                    Vt[(((size_t)b * Hn + h) * HDn + d) * TALLn + t] = v;
            }
}

// ---------------- flash attention over x-rows ----------------
// grid (T/64, B*H), 4 waves; wave w owns q rows [q0+16w, q0+16w+16).
// K tile (64 keys x 64 d) and V^T tile (64 d x 64 keys) staged with XOR swizzle
// slot = chunk ^ (row&7); P staged per-wave with the same swizzle.
__global__ __launch_bounds__(256) void k_attn(
        const unsigned short* __restrict__ Qb, const unsigned short* __restrict__ Kb,
        const unsigned short* __restrict__ Vt, unsigned short* __restrict__ Ob) {
    __shared__ __align__(16) unsigned short Ks[64 * 64];
    __shared__ __align__(16) unsigned short Vs[64 * 64];
    __shared__ __align__(16) unsigned short Ps[4 * 16 * 64];
    const int tid  = threadIdx.x;
    const int wave = tid >> 6;
    const int lane = tid & 63;
    const int g = lane >> 4, l16 = lane & 15;
    const int q0 = blockIdx.x * 64;        // x-local q base
    const int bh = blockIdx.y;
    const size_t kv = (size_t)bh * TALLn * HDn;

    // hoist Q fragments (A operand: row = lane&15, k = g*8.. ; two 32-wide k steps)
    bf16x8 qf[2];
    {
        const int tq = TPn + q0 + wave * 16 + l16;
        #pragma unroll
        for (int ks = 0; ks < 2; ++ks)
            qf[ks] = *reinterpret_cast<const bf16x8*>(
                Qb + kv + (size_t)tq * HDn + ks * 32 + g * 8);
    }

    f32x4 oacc[4] = {};
    float mrow[4] = {-1e30f, -1e30f, -1e30f, -1e30f};
    float lrow[4] = {0.f, 0.f, 0.f, 0.f};

    const int nkt = (TPn + q0) / 64 + 1;   // last tile is the diagonal one
    unsigned short* pbase = &Ps[wave * 16 * 64];

    for (int kt = 0; kt < nkt; ++kt) {
        const int kt0 = kt * 64;
        __syncthreads();                    // protect K/V LDS from prev-iter readers
        #pragma unroll
        for (int inst = 0; inst < 2; ++inst) {
            const int li = inst * 256 + tid;       // [0,512)
            const int row = li >> 3, slot = li & 7;
            const int chunk = slot ^ (row & 7);    // pre-swizzled global source
            ASYNC16(Kb + kv + (size_t)(kt0 + row) * HDn + chunk * 8,
                    &Ks[(inst * 256 + wave * 64) * 8]);
            ASYNC16(Vt + kv + (size_t)row * TALLn + kt0 + chunk * 8,
                    &Vs[(inst * 256 + wave * 64) * 8]);
        }
        __syncthreads();

        // S = Q K^T  (16 q x 64 keys per wave)
        f32x4 sacc[4] = {};
        #pragma unroll
        for (int ks = 0; ks < 2; ++ks)
            #pragma unroll
            for (int nt = 0; nt < 4; ++nt) {
                const int kr = nt * 16 + l16;
                const int slot = (ks * 4 + g) ^ (kr & 7);
                bf16x8 kf = *reinterpret_cast<const bf16x8*>(&Ks[kr * 64 + slot * 8]);
                sacc[nt] = __builtin_amdgcn_mfma_f32_16x16x32_bf16(
                        qf[ks], kf, sacc[nt], 0, 0, 0);
            }

        // online softmax; S layout: col(key)=lane&15, row(q)=g*4+r
        const bool diag = (kt == nkt - 1);
        const int qg0 = TPn + q0 + wave * 16 + g * 4;
        float p[4][4];
        #pragma unroll
        for (int r = 0; r < 4; ++r) {
            float mx = -1e30f;
            #pragma unroll
            for (int nt = 0; nt < 4; ++nt) {
                float s = sacc[nt][r] * 0.125f;
                if (diag && (kt0 + nt * 16 + l16) > (qg0 + r)) s = -1e30f;
                p[nt][r] = s;
                mx = fmaxf(mx, s);
            }
            mx = fmaxf(mx, __shfl_xor(mx, 1));
            mx = fmaxf(mx, __shfl_xor(mx, 2));
            mx = fmaxf(mx, __shfl_xor(mx, 4));
            mx = fmaxf(mx, __shfl_xor(mx, 8));
            const float mnew  = fmaxf(mrow[r], mx);
            const float alpha = __expf(mrow[r] - mnew);
            mrow[r] = mnew;
            float rs = 0.f;
            #pragma unroll
            for (int nt = 0; nt < 4; ++nt) {
                const float pe = __expf(p[nt][r] - mnew);
                p[nt][r] = pe;
                rs += pe;
            }
            rs += __shfl_xor(rs, 1);
            rs += __shfl_xor(rs, 2);
            rs += __shfl_xor(rs, 4);
            rs += __shfl_xor(rs, 8);
            lrow[r] = lrow[r] * alpha + rs;
            oacc[0][r] *= alpha;
            oacc[1][r] *= alpha;
            oacc[2][r] *= alpha;
            oacc[3][r] *= alpha;
        }

        // stage P (16 x 64 bf16 per wave), swizzled like K/V
        #pragma unroll
        for (int nt = 0; nt < 4; ++nt)
            #pragma unroll
            for (int r = 0; r < 4; ++r) {
                const int qrow = g * 4 + r;
                const int col  = nt * 16 + l16;
                const int slot = (col >> 3) ^ (qrow & 7);
                pbase[qrow * 64 + slot * 8 + (col & 7)] = f2bf(p[nt][r]);
            }

        // O += P V   (A = P: row=lane&15, k=key; B = V^T rows)
        #pragma unroll
        for (int ks = 0; ks < 2; ++ks) {
            const int slotp = (ks * 4 + g) ^ (l16 & 7);
            bf16x8 pf = *reinterpret_cast<const bf16x8*>(&pbase[l16 * 64 + slotp * 8]);
            #pragma unroll
            for (int nt = 0; nt < 4; ++nt) {
                const int vr = nt * 16 + l16;
                const int slotv = (ks * 4 + g) ^ (vr & 7);
                bf16x8 vf = *reinterpret_cast<const bf16x8*>(&Vs[vr * 64 + slotv * 8]);
                oacc[nt] = __builtin_amdgcn_mfma_f32_16x16x32_bf16(
                        pf, vf, oacc[nt], 0, 0, 0);
            }
        }
    }

    // normalize + store O as (B*T, C) bf16, (h,d) packed in C
    const int b = bh / Hn, h = bh - b * Hn;
    #pragma unroll
    for (int nt = 0; nt < 4; ++nt)
        #pragma unroll
        for (int r = 0; r < 4; ++r) {
            const int tl  = q0 + wave * 16 + g * 4 + r;
            const int col = h * HDn + nt * 16 + l16;
            Ob[((size_t)b * Tn + tl) * Cn + col] = f2bf(oacc[nt][r] / lrow[r]);
        }
}

// ---------------- out projection: (8192 x 768) @ (768 x 768)^T -> f32 ----------------
__global__ __launch_bounds__(256) void k_out_gemm(
        const unsigned short* __restrict__ A, const unsigned short* __restrict__ W,
        float* __restrict__ out) {
    __shared__ __align__(16) unsigned short As[128 * 32];
    __shared__ __align__(16) unsigned short Bs[128 * 32];
    const int tid  = threadIdx.x;
    const int wave = tid >> 6;
    const int lane = tid & 63;
    const int g = lane >> 4, l16 = lane & 15;
    const int m0 = blockIdx.x * 128, n0 = blockIdx.y * 128;
    const int wr = wave >> 1, wc = wave & 1;

    f32x4 acc[4][4] = {};

    for (int k0 = 0; k0 < Cn; k0 += 32) {
        #pragma unroll
        for (int inst = 0; inst < 2; ++inst) {
            const int li = inst * 256 + tid;
            const int row = li >> 2, slot = li & 3;
            const int chunk = slot ^ ((row >> 1) & 3);
            unsigned short* ldsA = &As[(inst * 256 + wave * 64) * 8];
            unsigned short* ldsB = &Bs[(inst * 256 + wave * 64) * 8];
            ASYNC16(A + (size_t)(m0 + row) * Cn + k0 + chunk * 8, ldsA);
            ASYNC16(W + (size_t)(n0 + row) * Cn + k0 + chunk * 8, ldsB);
        }
        __syncthreads();
        bf16x8 af[4], bfv[4];
        #pragma unroll
        for (int mt = 0; mt < 4; ++mt) {
            const int row = wr * 64 + mt * 16 + l16;
            const int slot = g ^ ((row >> 1) & 3);
            af[mt] = *reinterpret_cast<const bf16x8*>(&As[row * 32 + slot * 8]);
        }
        #pragma unroll
        for (int nt = 0; nt < 4; ++nt) {
            const int row = wc * 64 + nt * 16 + l16;
            const int slot = g ^ ((row >> 1) & 3);
            bfv[nt] = *reinterpret_cast<const bf16x8*>(&Bs[row * 32 + slot * 8]);
        }
        #pragma unroll
        for (int mt = 0; mt < 4; ++mt)
            #pragma unroll
            for (int nt = 0; nt < 4; ++nt)
                acc[mt][nt] = __builtin_amdgcn_mfma_f32_16x16x32_bf16(
                        af[mt], bfv[nt], acc[mt][nt], 0, 0, 0);
        __syncthreads();
    }

    #pragma unroll
    for (int mt = 0; mt < 4; ++mt)
        #pragma unroll
        for (int nt = 0; nt < 4; ++nt)
            #pragma unroll
            for (int r = 0; r < 4; ++r) {
                const int m = m0 + wr * 64 + mt * 16 + g * 4 + r;
                const int n = n0 + wc * 64 + nt * 16 + l16;
                out[(size_t)m * Cn + n] = acc[mt][nt][r];
            }
}

extern "C" void kernel_launch(void* const* d_in, const int* in_sizes, int n_in,
                              void* d_out, int out_size, void* d_ws, size_t ws_size,
                              hipStream_t stream) {
    const float* x    = (const float*)d_in[0];
    const float* pre  = (const float*)d_in[1];
    const float* wqkv = (const float*)d_in[2];
    const float* wout = (const float*)d_in[3];
    float* out = (float*)d_out;
    char* ws = (char*)d_ws;

    // workspace layout (bytes), total ~73.9 MB
    unsigned short* xf  = (unsigned short*)(ws + 0);          // B*TALL*C bf16 : 14,155,776
    unsigned short* wqb = (unsigned short*)(ws + 14155776);   // 3C*C bf16     :  3,538,944
    unsigned short* wob = (unsigned short*)(ws + 17694720);   // C*C bf16      :  1,179,648
    unsigned short* Qb  = (unsigned short*)(ws + 18874368);   // B,H,TALL,HD   : 14,155,776
    unsigned short* Kb  = (unsigned short*)(ws + 33030144);   // B,H,TALL,HD   : 14,155,776
    unsigned short* Vt  = (unsigned short*)(ws + 47185920);   // B,H,HD,TALL   : 14,155,776
    unsigned short* Ob  = (unsigned short*)(ws + 61341696);   // B*T,C bf16    : 12,582,912

    k_build_xfull<<<dim3((Bn * TALLn * Cn / 4) / 256), 256, 0, stream>>>(x, pre, xf);
    k_cast<<<dim3((3 * Cn * Cn / 4) / 256), 256, 0, stream>>>(wqkv, wqb);
    k_cast<<<dim3((Cn * Cn / 4) / 256), 256, 0, stream>>>(wout, wob);
    k_qkv_gemm<<<dim3((Bn * TALLn) / 128, (3 * Cn) / 128), 256, 0, stream>>>(
            xf, wqb, Qb, Kb, Vt);
    k_attn<<<dim3(Tn / 64, Bn * Hn), 256, 0, stream>>>(Qb, Kb, Vt, Ob);
    k_out_gemm<<<dim3((Bn * Tn) / 128, Cn / 128), 256, 0, stream>>>(Ob, wob, out);
}

// Round 2
// 222.195 us; speedup vs baseline: 1.4201x; 1.4201x over previous
//
#include <hip/hip_runtime.h>

// Problem constants
constexpr int Bn   = 4;
constexpr int Tn   = 2048;
constexpr int TPn  = 256;
constexpr int TALLn = 2304;   // TPn + Tn
constexpr int Cn   = 768;
constexpr int Hn   = 12;
constexpr int HDn  = 64;

typedef __bf16 bf16x8 __attribute__((ext_vector_type(8)));
typedef float  f32x4  __attribute__((ext_vector_type(4)));

// RNE float -> bf16 bits (finite inputs only)
__device__ __forceinline__ unsigned short f2bf(float f) {
    unsigned int x = __float_as_uint(f);
    x += 0x7fffu + ((x >> 16) & 1u);
    return (unsigned short)(x >> 16);
}

// async global->LDS, 16B per lane; lds dst must be wave-uniform base (HW appends lane*16)
#define ASYNC16(gsrc, ldst)                                                           \
    __builtin_amdgcn_global_load_lds((__attribute__((address_space(1))) void*)(gsrc), \
                                     (__attribute__((address_space(3))) void*)(ldst), \
                                     16, 0, 0)

// ---------------- cast kernels ----------------
__global__ __launch_bounds__(256) void k_build_xfull(
        const float* __restrict__ x, const float* __restrict__ pre,
        unsigned short* __restrict__ xf) {
    int idx = blockIdx.x * 256 + threadIdx.x;           // one float4 per thread
    int row = idx / (Cn / 4);                           // token row in (B*TALL)
    int c   = (idx - row * (Cn / 4)) * 4;
    int b = row / TALLn, tt = row - b * TALLn;
    const float* src = (tt < TPn) ? pre + ((size_t)b * TPn + tt) * Cn + c
                                  : x   + ((size_t)b * Tn + (tt - TPn)) * Cn + c;
    float4 f = *reinterpret_cast<const float4*>(src);
    ushort4 o = { f2bf(f.x), f2bf(f.y), f2bf(f.z), f2bf(f.w) };
    *reinterpret_cast<ushort4*>(xf + (size_t)row * Cn + c) = o;
}

__global__ __launch_bounds__(256) void k_cast(
        const float* __restrict__ in, unsigned short* __restrict__ out) {
    int idx = (blockIdx.x * 256 + threadIdx.x) * 4;
    float4 f = *reinterpret_cast<const float4*>(in + idx);
    ushort4 o = { f2bf(f.x), f2bf(f.y), f2bf(f.z), f2bf(f.w) };
    *reinterpret_cast<ushort4*>(out + idx) = o;
}

// ---------------- QKV GEMM: (9216 x 768) @ (2304 x 768)^T ----------------
// 128x128 tile, BK=64, 4 waves (2x2), wave computes 64x64 via 4x4 16x16x32 MFMAs.
// LDS rows are 64 shorts (128B); slot(chunk) swizzle: slot = chunk ^ (row&7).
__global__ __launch_bounds__(256) void k_qkv_gemm(
        const unsigned short* __restrict__ A, const unsigned short* __restrict__ W,
        unsigned short* __restrict__ Qb, unsigned short* __restrict__ Kb,
        unsigned short* __restrict__ Vt) {
    __shared__ __align__(16) unsigned short smem[16384];   // A:0..8191, B:8192..16383
    unsigned short* As = smem;
    unsigned short* Bs = smem + 8192;
    const int tid  = threadIdx.x;
    const int wave = tid >> 6;
    const int lane = tid & 63;
    const int g = lane >> 4, l16 = lane & 15;
    const int m0 = blockIdx.x * 128, n0 = blockIdx.y * 128;
    const int wr = wave >> 1, wc = wave & 1;

    f32x4 acc[4][4] = {};

    for (int k0 = 0; k0 < Cn; k0 += 64) {
        #pragma unroll
        for (int inst = 0; inst < 4; ++inst) {
            const int li = inst * 256 + tid;            // [0,1024)
            const int row = li >> 3, slot = li & 7;
            const int ch = slot ^ (row & 7);            // inverse-swizzled source
            ASYNC16(A + (size_t)(m0 + row) * Cn + k0 + ch * 8,
                    &As[(inst * 256 + wave * 64) * 8]);
            ASYNC16(W + (size_t)(n0 + row) * Cn + k0 + ch * 8,
                    &Bs[(inst * 256 + wave * 64) * 8]);
        }
        __syncthreads();
        #pragma unroll
        for (int kk = 0; kk < 2; ++kk) {
            bf16x8 af[4], bfv[4];
            #pragma unroll
            for (int mt = 0; mt < 4; ++mt) {
                const int row = wr * 64 + mt * 16 + l16;
                const int slot = (kk * 4 + g) ^ (row & 7);
                af[mt] = *reinterpret_cast<const bf16x8*>(&As[row * 64 + slot * 8]);
            }
            #pragma unroll
            for (int nt = 0; nt < 4; ++nt) {
                const int row = wc * 64 + nt * 16 + l16;
                const int slot = (kk * 4 + g) ^ (row & 7);
                bfv[nt] = *reinterpret_cast<const bf16x8*>(&Bs[row * 64 + slot * 8]);
            }
            #pragma unroll
            for (int mt = 0; mt < 4; ++mt)
                #pragma unroll
                for (int nt = 0; nt < 4; ++nt)
                    acc[mt][nt] = __builtin_amdgcn_mfma_f32_16x16x32_bf16(
                            af[mt], bfv[nt], acc[mt][nt], 0, 0, 0);
        }
        __syncthreads();
    }

    // epilogue
    const int b   = m0 / TALLn;        // 2304 % 128 == 0
    const int t0  = m0 - b * TALLn;
    const int sel = n0 / Cn;           // 768 % 128 == 0
    const int hn0 = n0 - sel * Cn;

    if (sel == 2) {
        // V: transpose 128x128 tile via LDS, then coalesced 16B stores to V^T.
        // Element (t,hn) stored at smem[hn*128 + ((t>>3)^(hn&7))*8 + (t&7)].
        #pragma unroll
        for (int mt = 0; mt < 4; ++mt)
            #pragma unroll
            for (int nt = 0; nt < 4; ++nt)
                #pragma unroll
                for (int r = 0; r < 4; ++r) {
                    const int t  = wr * 64 + mt * 16 + g * 4 + r;
                    const int hn = wc * 64 + nt * 16 + l16;
                    smem[hn * 128 + (((t >> 3) ^ (hn & 7)) << 3) + (t & 7)] =
                            f2bf(acc[mt][nt][r]);
                }
        __syncthreads();
        #pragma unroll
        for (int j = 0; j < 8; ++j) {
            const int u  = tid + 256 * j;
            const int hn = u >> 4, tc = u & 15;
            bf16x8 v = *reinterpret_cast<const bf16x8*>(
                    &smem[hn * 128 + ((tc ^ (hn & 7)) << 3)]);
            const int hh = (hn0 + hn) >> 6;
            const int dd = hn & 63;
            *reinterpret_cast<bf16x8*>(
                    &Vt[(((size_t)b * Hn + hh) * HDn + dd) * TALLn + t0 + tc * 8]) = v;
        }
    } else {
        #pragma unroll
        for (int mt = 0; mt < 4; ++mt)
            #pragma unroll
            for (int nt = 0; nt < 4; ++nt)
                #pragma unroll
                for (int r = 0; r < 4; ++r) {
                    const int t  = t0 + wr * 64 + mt * 16 + g * 4 + r;
                    const int hn = hn0 + wc * 64 + nt * 16 + l16;
                    const int h = hn >> 6, d = hn & 63;
                    const unsigned short v = f2bf(acc[mt][nt][r]);
                    if (sel == 0)
                        Qb[(((size_t)b * Hn + h) * TALLn + t) * HDn + d] = v;
                    else
                        Kb[(((size_t)b * Hn + h) * TALLn + t) * HDn + d] = v;
                }
    }
}

// ---------------- flash attention over x-rows ----------------
// grid (16, B*H): block handles q-chunk pair (pi, 31-pi) -> always 41 K-tiles.
// 4 waves; wave w owns 16 q rows of the active 64-row chunk. K/V double-buffered
// in LDS (stage next tile before computing current; one barrier per tile).
__global__ __launch_bounds__(256) void k_attn(
        const unsigned short* __restrict__ Qb, const unsigned short* __restrict__ Kb,
        const unsigned short* __restrict__ Vt, unsigned short* __restrict__ Ob) {
    __shared__ __align__(16) unsigned short Ks[2][4096];
    __shared__ __align__(16) unsigned short Vs[2][4096];
    __shared__ __align__(16) unsigned short Ps[4096];
    const int tid  = threadIdx.x;
    const int wave = tid >> 6;
    const int lane = tid & 63;
    const int g = lane >> 4, l16 = lane & 15;
    const int pi = blockIdx.x;             // pair index 0..15
    const int bh = blockIdx.y;
    const size_t kv = (size_t)bh * TALLn * HDn;
    unsigned short* pbase = &Ps[wave * 1024];
    constexpr float SC = 0.18033688f;      // (1/8) * log2(e)

    bf16x8 qf[2];
    auto loadQ = [&](int ch) {
        const int tq = TPn + ch * 64 + wave * 16 + l16;
        #pragma unroll
        for (int ks = 0; ks < 2; ++ks)
            qf[ks] = *reinterpret_cast<const bf16x8*>(
                    Qb + kv + (size_t)tq * HDn + ks * 32 + g * 8);
    };
    auto stageKV = [&](int bs, int kt0) {
        #pragma unroll
        for (int inst = 0; inst < 2; ++inst) {
            const int li = inst * 256 + tid;       // [0,512)
            const int row = li >> 3, slot = li & 7;
            const int ch = slot ^ (row & 7);       // pre-swizzled global source
            ASYNC16(Kb + kv + (size_t)(kt0 + row) * HDn + ch * 8,
                    &Ks[bs][(inst * 256 + wave * 64) * 8]);
            ASYNC16(Vt + kv + (size_t)row * TALLn + kt0 + ch * 8,
                    &Vs[bs][(inst * 256 + wave * 64) * 8]);
        }
    };

    f32x4 oacc[4];
    float mrow[4], lrow[4];
    #pragma unroll
    for (int i = 0; i < 4; ++i) {
        mrow[i] = -1e30f; lrow[i] = 0.f;
        #pragma unroll
        for (int e = 0; e < 4; ++e) oacc[i][e] = 0.f;
    }

    const int b = bh / Hn, h = bh - b * Hn;
    auto storeO = [&](int ch) {
        #pragma unroll
        for (int nt = 0; nt < 4; ++nt)
            #pragma unroll
            for (int r = 0; r < 4; ++r) {
                const int tl  = ch * 64 + wave * 16 + g * 4 + r;
                const int col = h * HDn + nt * 16 + l16;
                Ob[((size_t)b * Tn + tl) * Cn + col] = f2bf(oacc[nt][r] / lrow[r]);
            }
    };

    int chunk = pi;
    int nkt   = 5 + pi;                    // tiles for chunk A
    int kt = 0, buf = 0;
    loadQ(chunk);
    stageKV(0, 0);
    __syncthreads();

    for (int t = 0; t < 41; ++t) {
        if (t < 40) {                       // prefetch next tile (wraps to chunk B)
            const int nk0 = (kt + 1 < nkt) ? (kt + 1) * 64 : 0;
            stageKV(buf ^ 1, nk0);
        }

        // ---- compute tile (chunk, kt) from buf ----
        const int kt0 = kt * 64;
        f32x4 sacc[4] = {};
        #pragma unroll
        for (int ks = 0; ks < 2; ++ks)
            #pragma unroll
            for (int nt = 0; nt < 4; ++nt) {
                const int kr = nt * 16 + l16;
                const int slot = (ks * 4 + g) ^ (kr & 7);
                bf16x8 kf = *reinterpret_cast<const bf16x8*>(&Ks[buf][kr * 64 + slot * 8]);
                sacc[nt] = __builtin_amdgcn_mfma_f32_16x16x32_bf16(
                        qf[ks], kf, sacc[nt], 0, 0, 0);
            }

        const bool diag = (kt == nkt - 1);
        const int qg0 = TPn + chunk * 64 + wave * 16 + g * 4;
        float p[4][4];
        #pragma unroll
        for (int r = 0; r < 4; ++r) {
            float mx = -1e30f;
            #pragma unroll
            for (int nt = 0; nt < 4; ++nt) {
                float s = sacc[nt][r] * SC;            // log2 domain
                if (diag && (kt0 + nt * 16 + l16) > (qg0 + r)) s = -1e30f;
                p[nt][r] = s;
                mx = fmaxf(mx, s);
            }
            mx = fmaxf(mx, __shfl_xor(mx, 1));
            mx = fmaxf(mx, __shfl_xor(mx, 2));
            mx = fmaxf(mx, __shfl_xor(mx, 4));
            mx = fmaxf(mx, __shfl_xor(mx, 8));
            const float mnew  = fmaxf(mrow[r], mx);
            const float alpha = exp2f(mrow[r] - mnew);
            mrow[r] = mnew;
            float rs = 0.f;
            #pragma unroll
            for (int nt = 0; nt < 4; ++nt) {
                const float pe = exp2f(p[nt][r] - mnew);
                p[nt][r] = pe;
                rs += pe;
            }
            rs += __shfl_xor(rs, 1);
            rs += __shfl_xor(rs, 2);
            rs += __shfl_xor(rs, 4);
            rs += __shfl_xor(rs, 8);
            lrow[r] = lrow[r] * alpha + rs;
            oacc[0][r] *= alpha;
            oacc[1][r] *= alpha;
            oacc[2][r] *= alpha;
            oacc[3][r] *= alpha;
        }

        // stage P (16 x 64 bf16 per wave), swizzled like K/V
        #pragma unroll
        for (int nt = 0; nt < 4; ++nt)
            #pragma unroll
            for (int r = 0; r < 4; ++r) {
                const int qrow = g * 4 + r;
                const int col  = nt * 16 + l16;
                const int slot = (col >> 3) ^ (qrow & 7);
                pbase[qrow * 64 + slot * 8 + (col & 7)] = f2bf(p[nt][r]);
            }

        // O += P V
        #pragma unroll
        for (int ks = 0; ks < 2; ++ks) {
            const int slotp = (ks * 4 + g) ^ (l16 & 7);
            bf16x8 pf = *reinterpret_cast<const bf16x8*>(&pbase[l16 * 64 + slotp * 8]);
            #pragma unroll
            for (int nt = 0; nt < 4; ++nt) {
                const int vr = nt * 16 + l16;
                const int slotv = (ks * 4 + g) ^ (vr & 7);
                bf16x8 vf = *reinterpret_cast<const bf16x8*>(&Vs[buf][vr * 64 + slotv * 8]);
                oacc[nt] = __builtin_amdgcn_mfma_f32_16x16x32_bf16(
                        pf, vf, oacc[nt], 0, 0, 0);
            }
        }

        // ---- chunk boundary / advance ----
        if (kt == nkt - 1) {
            storeO(chunk);
            if (t < 40) {
                chunk = 31 - pi;
                nkt   = 36 - pi;
                kt = 0;
                #pragma unroll
                for (int i = 0; i < 4; ++i) {
                    mrow[i] = -1e30f; lrow[i] = 0.f;
                    #pragma unroll
                    for (int e = 0; e < 4; ++e) oacc[i][e] = 0.f;
                }
                loadQ(chunk);
            }
        } else {
            ++kt;
        }
        buf ^= 1;
        __syncthreads();   // drains vmcnt(0): next tile's staging is complete
    }
}

// ---------------- out projection: (8192 x 768) @ (768 x 768)^T -> f32 ----------------
__global__ __launch_bounds__(256) void k_out_gemm(
        const unsigned short* __restrict__ A, const unsigned short* __restrict__ W,
        float* __restrict__ out) {
    __shared__ __align__(16) unsigned short As[8192];
    __shared__ __align__(16) unsigned short Bs[8192];
    const int tid  = threadIdx.x;
    const int wave = tid >> 6;
    const int lane = tid & 63;
    const int g = lane >> 4, l16 = lane & 15;
    const int m0 = blockIdx.x * 128, n0 = blockIdx.y * 128;
    const int wr = wave >> 1, wc = wave & 1;

    f32x4 acc[4][4] = {};

    for (int k0 = 0; k0 < Cn; k0 += 64) {
        #pragma unroll
        for (int inst = 0; inst < 4; ++inst) {
            const int li = inst * 256 + tid;
            const int row = li >> 3, slot = li & 7;
            const int ch = slot ^ (row & 7);
            ASYNC16(A + (size_t)(m0 + row) * Cn + k0 + ch * 8,
                    &As[(inst * 256 + wave * 64) * 8]);
            ASYNC16(W + (size_t)(n0 + row) * Cn + k0 + ch * 8,
                    &Bs[(inst * 256 + wave * 64) * 8]);
        }
        __syncthreads();
        #pragma unroll
        for (int kk = 0; kk < 2; ++kk) {
            bf16x8 af[4], bfv[4];
            #pragma unroll
            for (int mt = 0; mt < 4; ++mt) {
                const int row = wr * 64 + mt * 16 + l16;
                const int slot = (kk * 4 + g) ^ (row & 7);
                af[mt] = *reinterpret_cast<const bf16x8*>(&As[row * 64 + slot * 8]);
            }
            #pragma unroll
            for (int nt = 0; nt < 4; ++nt) {
                const int row = wc * 64 + nt * 16 + l16;
                const int slot = (kk * 4 + g) ^ (row & 7);
                bfv[nt] = *reinterpret_cast<const bf16x8*>(&Bs[row * 64 + slot * 8]);
            }
            #pragma unroll
            for (int mt = 0; mt < 4; ++mt)
                #pragma unroll
                for (int nt = 0; nt < 4; ++nt)
                    acc[mt][nt] = __builtin_amdgcn_mfma_f32_16x16x32_bf16(
                            af[mt], bfv[nt], acc[mt][nt], 0, 0, 0);
        }
        __syncthreads();
    }

    #pragma unroll
    for (int mt = 0; mt < 4; ++mt)
        #pragma unroll
        for (int nt = 0; nt < 4; ++nt)
            #pragma unroll
            for (int r = 0; r < 4; ++r) {
                const int m = m0 + wr * 64 + mt * 16 + g * 4 + r;
                const int n = n0 + wc * 64 + nt * 16 + l16;
                out[(size_t)m * Cn + n] = acc[mt][nt][r];
            }
}

extern "C" void kernel_launch(void* const* d_in, const int* in_sizes, int n_in,
                              void* d_out, int out_size, void* d_ws, size_t ws_size,
                              hipStream_t stream) {
    const float* x    = (const float*)d_in[0];
    const float* pre  = (const float*)d_in[1];
    const float* wqkv = (const float*)d_in[2];
    const float* wout = (const float*)d_in[3];
    float* out = (float*)d_out;
    char* ws = (char*)d_ws;

    unsigned short* xf  = (unsigned short*)(ws + 0);          // B*TALL*C bf16
    unsigned short* wqb = (unsigned short*)(ws + 14155776);   // 3C*C bf16
    unsigned short* wob = (unsigned short*)(ws + 17694720);   // C*C bf16
    unsigned short* Qb  = (unsigned short*)(ws + 18874368);   // B,H,TALL,HD
    unsigned short* Kb  = (unsigned short*)(ws + 33030144);   // B,H,TALL,HD
    unsigned short* Vt  = (unsigned short*)(ws + 47185920);   // B,H,HD,TALL
    unsigned short* Ob  = (unsigned short*)(ws + 61341696);   // B*T,C bf16

    k_build_xfull<<<dim3((Bn * TALLn * Cn / 4) / 256), 256, 0, stream>>>(x, pre, xf);
    k_cast<<<dim3((3 * Cn * Cn / 4) / 256), 256, 0, stream>>>(wqkv, wqb);
    k_cast<<<dim3((Cn * Cn / 4) / 256), 256, 0, stream>>>(wout, wob);
    k_qkv_gemm<<<dim3((Bn * TALLn) / 128, (3 * Cn) / 128), 256, 0, stream>>>(
            xf, wqb, Qb, Kb, Vt);
    k_attn<<<dim3(16, Bn * Hn), 256, 0, stream>>>(Qb, Kb, Vt, Ob);
    k_out_gemm<<<dim3((Bn * Tn) / 128, Cn / 128), 256, 0, stream>>>(Ob, wob, out);
}

// Round 3
// 205.894 us; speedup vs baseline: 1.5325x; 1.0792x over previous
//
#include <hip/hip_runtime.h>

// Problem constants
constexpr int Bn   = 4;
constexpr int Tn   = 2048;
constexpr int TPn  = 256;
constexpr int TALLn = 2304;   // TPn + Tn
constexpr int Cn   = 768;
constexpr int Hn   = 12;
constexpr int HDn  = 64;

typedef __bf16 bf16x8 __attribute__((ext_vector_type(8)));
typedef float  f32x4  __attribute__((ext_vector_type(4)));
typedef float  f32x16 __attribute__((ext_vector_type(16)));
typedef unsigned u32x4 __attribute__((ext_vector_type(4)));

// RNE float -> bf16 bits (finite inputs only)
__device__ __forceinline__ unsigned short f2bf(float f) {
    unsigned int x = __float_as_uint(f);
    x += 0x7fffu + ((x >> 16) & 1u);
    return (unsigned short)(x >> 16);
}

__device__ __forceinline__ unsigned pack2bf(float a, float b) {
    return (unsigned)f2bf(a) | ((unsigned)f2bf(b) << 16);
}

// async global->LDS, 16B per lane; lds dst must be wave-uniform base (HW appends lane*16)
#define ASYNC16(gsrc, ldst)                                                           \
    __builtin_amdgcn_global_load_lds((__attribute__((address_space(1))) void*)(gsrc), \
                                     (__attribute__((address_space(3))) void*)(ldst), \
                                     16, 0, 0)

// ---------------- cast kernels ----------------
__global__ __launch_bounds__(256) void k_build_xfull(
        const float* __restrict__ x, const float* __restrict__ pre,
        unsigned short* __restrict__ xf) {
    int idx = blockIdx.x * 256 + threadIdx.x;           // one float4 per thread
    int row = idx / (Cn / 4);                           // token row in (B*TALL)
    int c   = (idx - row * (Cn / 4)) * 4;
    int b = row / TALLn, tt = row - b * TALLn;
    const float* src = (tt < TPn) ? pre + ((size_t)b * TPn + tt) * Cn + c
                                  : x   + ((size_t)b * Tn + (tt - TPn)) * Cn + c;
    float4 f = *reinterpret_cast<const float4*>(src);
    ushort4 o = { f2bf(f.x), f2bf(f.y), f2bf(f.z), f2bf(f.w) };
    *reinterpret_cast<ushort4*>(xf + (size_t)row * Cn + c) = o;
}

__global__ __launch_bounds__(256) void k_cast(
        const float* __restrict__ in, unsigned short* __restrict__ out) {
    int idx = (blockIdx.x * 256 + threadIdx.x) * 4;
    float4 f = *reinterpret_cast<const float4*>(in + idx);
    ushort4 o = { f2bf(f.x), f2bf(f.y), f2bf(f.z), f2bf(f.w) };
    *reinterpret_cast<ushort4*>(out + idx) = o;
}

// ---------------- QKV GEMM: (9216 x 768) @ (2304 x 768)^T ----------------
// 128x128 tile, BK=64, 4 waves (2x2), wave computes 64x64 via 4x4 16x16x32 MFMAs.
// LDS rows are 64 shorts (128B); slot(chunk) swizzle: slot = chunk ^ (row&7).
// Q output is pre-scaled by (1/8)*log2(e) so attention softmax runs in exp2 domain.
__global__ __launch_bounds__(256) void k_qkv_gemm(
        const unsigned short* __restrict__ A, const unsigned short* __restrict__ W,
        unsigned short* __restrict__ Qb, unsigned short* __restrict__ Kb,
        unsigned short* __restrict__ Vt) {
    __shared__ __align__(16) unsigned short smem[16384];   // A:0..8191, B:8192..16383
    unsigned short* As = smem;
    unsigned short* Bs = smem + 8192;
    const int tid  = threadIdx.x;
    const int wave = tid >> 6;
    const int lane = tid & 63;
    const int g = lane >> 4, l16 = lane & 15;
    const int m0 = blockIdx.x * 128, n0 = blockIdx.y * 128;
    const int wr = wave >> 1, wc = wave & 1;

    f32x4 acc[4][4] = {};

    for (int k0 = 0; k0 < Cn; k0 += 64) {
        #pragma unroll
        for (int inst = 0; inst < 4; ++inst) {
            const int li = inst * 256 + tid;            // [0,1024)
            const int row = li >> 3, slot = li & 7;
            const int ch = slot ^ (row & 7);            // inverse-swizzled source
            ASYNC16(A + (size_t)(m0 + row) * Cn + k0 + ch * 8,
                    &As[(inst * 256 + wave * 64) * 8]);
            ASYNC16(W + (size_t)(n0 + row) * Cn + k0 + ch * 8,
                    &Bs[(inst * 256 + wave * 64) * 8]);
        }
        __syncthreads();
        #pragma unroll
        for (int kk = 0; kk < 2; ++kk) {
            bf16x8 af[4], bfv[4];
            #pragma unroll
            for (int mt = 0; mt < 4; ++mt) {
                const int row = wr * 64 + mt * 16 + l16;
                const int slot = (kk * 4 + g) ^ (row & 7);
                af[mt] = *reinterpret_cast<const bf16x8*>(&As[row * 64 + slot * 8]);
            }
            #pragma unroll
            for (int nt = 0; nt < 4; ++nt) {
                const int row = wc * 64 + nt * 16 + l16;
                const int slot = (kk * 4 + g) ^ (row & 7);
                bfv[nt] = *reinterpret_cast<const bf16x8*>(&Bs[row * 64 + slot * 8]);
            }
            #pragma unroll
            for (int mt = 0; mt < 4; ++mt)
                #pragma unroll
                for (int nt = 0; nt < 4; ++nt)
                    acc[mt][nt] = __builtin_amdgcn_mfma_f32_16x16x32_bf16(
                            af[mt], bfv[nt], acc[mt][nt], 0, 0, 0);
        }
        __syncthreads();
    }

    // epilogue
    const int b   = m0 / TALLn;        // 2304 % 128 == 0
    const int t0  = m0 - b * TALLn;
    const int sel = n0 / Cn;           // 768 % 128 == 0
    const int hn0 = n0 - sel * Cn;
    constexpr float SCQ = 0.18033688011112042f;   // (1/8) * log2(e)

    if (sel == 2) {
        // V: transpose 128x128 tile via LDS, then coalesced 16B stores to V^T.
        #pragma unroll
        for (int mt = 0; mt < 4; ++mt)
            #pragma unroll
            for (int nt = 0; nt < 4; ++nt)
                #pragma unroll
                for (int r = 0; r < 4; ++r) {
                    const int t  = wr * 64 + mt * 16 + g * 4 + r;
                    const int hn = wc * 64 + nt * 16 + l16;
                    smem[hn * 128 + (((t >> 3) ^ (hn & 7)) << 3) + (t & 7)] =
                            f2bf(acc[mt][nt][r]);
                }
        __syncthreads();
        #pragma unroll
        for (int j = 0; j < 8; ++j) {
            const int u  = tid + 256 * j;
            const int hn = u >> 4, tc = u & 15;
            bf16x8 v = *reinterpret_cast<const bf16x8*>(
                    &smem[hn * 128 + ((tc ^ (hn & 7)) << 3)]);
            const int hh = (hn0 + hn) >> 6;
            const int dd = hn & 63;
            *reinterpret_cast<bf16x8*>(
                    &Vt[(((size_t)b * Hn + hh) * HDn + dd) * TALLn + t0 + tc * 8]) = v;
        }
    } else {
        #pragma unroll
        for (int mt = 0; mt < 4; ++mt)
            #pragma unroll
            for (int nt = 0; nt < 4; ++nt)
                #pragma unroll
                for (int r = 0; r < 4; ++r) {
                    const int t  = t0 + wr * 64 + mt * 16 + g * 4 + r;
                    const int hn = hn0 + wc * 64 + nt * 16 + l16;
                    const int h = hn >> 6, d = hn & 63;
                    if (sel == 0)
                        Qb[(((size_t)b * Hn + h) * TALLn + t) * HDn + d] =
                                f2bf(acc[mt][nt][r] * SCQ);
                    else
                        Kb[(((size_t)b * Hn + h) * TALLn + t) * HDn + d] =
                                f2bf(acc[mt][nt][r]);
                }
    }
}

// ---------------- flash attention over x-rows (swapped 32x32 structure) -------------
// 768 blocks of 128 threads (2 waves x 32 q rows = 64-q chunk), chunk pair (pi,31-pi)
// -> 41 K-tiles per block, exactly even. XCD swizzle groups same-(b,h) blocks per XCD.
// S^T = mfma32x32(K, Q): col = q = lane&31 -> softmax reduce is in-lane + 1 shfl_xor32.
// P redistributed in-register (shfl_xor 32) to form PV B-operand; O^T accumulated.
__global__ __launch_bounds__(128) void k_attn(
        const unsigned short* __restrict__ Qb, const unsigned short* __restrict__ Kb,
        const unsigned short* __restrict__ Vt, unsigned short* __restrict__ Ob) {
    __shared__ __align__(16) unsigned short Ks[2][4096];
    __shared__ __align__(16) unsigned short Vs[2][4096];
    const int tid  = threadIdx.x;
    const int wave = tid >> 6;
    const int lane = tid & 63;
    const int l32  = lane & 31;
    const int hi   = lane >> 5;

    // XCD swizzle: consecutive HW blocks round-robin XCDs; give each XCD 6 whole bh.
    const int fb = blockIdx.x;            // 0..767
    const int j  = fb >> 3;
    const int bh = 6 * (fb & 7) + (j >> 4);
    const int pi = j & 15;
    const size_t kv = (size_t)bh * TALLn * HDn;

    bf16x8 qf[4];
    auto loadQ = [&](int ch) {
        const int tq = TPn + ch * 64 + wave * 32 + l32;
        #pragma unroll
        for (int s = 0; s < 4; ++s)
            qf[s] = *reinterpret_cast<const bf16x8*>(
                    Qb + kv + (size_t)tq * HDn + s * 16 + hi * 8);
    };
    auto stageKV = [&](int bs, int kt0) {
        #pragma unroll
        for (int inst = 0; inst < 4; ++inst) {
            const int li = inst * 128 + tid;       // [0,512)
            const int row = li >> 3, slot = li & 7;
            const int ch = slot ^ (row & 7);       // pre-swizzled global source
            ASYNC16(Kb + kv + (size_t)(kt0 + row) * HDn + ch * 8,
                    &Ks[bs][(inst * 128 + wave * 64) * 8]);
            ASYNC16(Vt + kv + (size_t)row * TALLn + kt0 + ch * 8,
                    &Vs[bs][(inst * 128 + wave * 64) * 8]);
        }
    };

    f32x16 oacc[2] = {};
    float mrow = -1e30f, lrow = 0.f;

    const int b = bh / Hn, h = bh - b * Hn;
    auto storeO = [&](int ch) {
        const float inv = 1.0f / lrow;
        const size_t row = (size_t)b * Tn + ch * 64 + wave * 32 + l32;
        #pragma unroll
        for (int dt = 0; dt < 2; ++dt)
            #pragma unroll
            for (int t4 = 0; t4 < 4; ++t4) {
                ushort4 st;
                st.x = f2bf(oacc[dt][4 * t4 + 0] * inv);
                st.y = f2bf(oacc[dt][4 * t4 + 1] * inv);
                st.z = f2bf(oacc[dt][4 * t4 + 2] * inv);
                st.w = f2bf(oacc[dt][4 * t4 + 3] * inv);
                const int d0 = dt * 32 + 4 * hi + 8 * t4;
                *reinterpret_cast<ushort4*>(&Ob[row * Cn + h * 64 + d0]) = st;
            }
    };

    int chunk = pi;
    int nkt   = 5 + pi;
    int kt = 0, buf = 0;
    loadQ(chunk);
    stageKV(0, 0);
    __syncthreads();

    for (int t = 0; t < 41; ++t) {
        if (t < 40) {                       // prefetch next tile (wraps to chunk B)
            const int nk0 = (kt + 1 < nkt) ? (kt + 1) * 64 : 0;
            stageKV(buf ^ 1, nk0);
        }

        // ---- S^T = K * Q over 64 keys (two 32-key tiles), k = 64 dims ----
        f32x16 s0 = {}, s1 = {};
        #pragma unroll
        for (int s = 0; s < 4; ++s) {
            const int sl = ((2 * s + hi) ^ (l32 & 7)) * 8;
            bf16x8 k0 = *reinterpret_cast<const bf16x8*>(&Ks[buf][l32 * 64 + sl]);
            bf16x8 k1 = *reinterpret_cast<const bf16x8*>(&Ks[buf][(32 + l32) * 64 + sl]);
            s0 = __builtin_amdgcn_mfma_f32_32x32x16_bf16(k0, qf[s], s0, 0, 0, 0);
            s1 = __builtin_amdgcn_mfma_f32_32x32x16_bf16(k1, qf[s], s1, 0, 0, 0);
        }

        // ---- online softmax (q = l32 is lane-local; rows = keys in-lane) ----
        const int kt0v = kt * 64;
        const bool diag = (kt == nkt - 1);
        const int qg = TPn + chunk * 64 + wave * 32 + l32;
        const int lim = diag ? (qg - kt0v) : 0x7fffffff;   // allowed local key <= lim
        float pm = -1e30f;
        #pragma unroll
        for (int r = 0; r < 16; ++r) {
            const int ro = (r & 3) + 8 * (r >> 2) + 4 * hi;
            const float v0 = (ro <= lim) ? s0[r] : -1e30f;
            const float v1 = (32 + ro <= lim) ? s1[r] : -1e30f;
            s0[r] = v0; s1[r] = v1;
            pm = fmaxf(pm, fmaxf(v0, v1));
        }
        pm = fmaxf(pm, __shfl_xor(pm, 32));
        const float mnew  = fmaxf(mrow, pm);
        const float alpha = exp2f(mrow - mnew);
        mrow = mnew;

        float rs = 0.f;
        unsigned dw[2][8];
        #pragma unroll
        for (int i = 0; i < 8; ++i) {
            const float e0 = exp2f(s0[2 * i] - mnew);
            const float e1 = exp2f(s0[2 * i + 1] - mnew);
            const float e2 = exp2f(s1[2 * i] - mnew);
            const float e3 = exp2f(s1[2 * i + 1] - mnew);
            rs += (e0 + e1) + (e2 + e3);
            dw[0][i] = pack2bf(e0, e1);
            dw[1][i] = pack2bf(e2, e3);
        }
        rs += __shfl_xor(rs, 32);
        lrow = lrow * alpha + rs;
        #pragma unroll
        for (int r = 0; r < 16; ++r) { oacc[0][r] *= alpha; oacc[1][r] *= alpha; }

        // ---- O^T += V^T * P^T : assemble P B-operand in-register ----
        #pragma unroll
        for (int kt4 = 0; kt4 < 4; ++kt4) {
            const int tt = kt4 >> 1, c0 = 4 * (kt4 & 1);
            unsigned w01[2], w23[2];
            #pragma unroll
            for (int bb = 0; bb < 2; ++bb) {
                const unsigned shA = __shfl_xor(dw[tt][c0 + 2 + bb], 32);
                const unsigned shB = __shfl_xor(dw[tt][c0 + bb], 32);
                w01[bb] = hi ? shA : dw[tt][c0 + bb];
                w23[bb] = hi ? dw[tt][c0 + 2 + bb] : shB;
            }
            const u32x4 uu = { w01[0], w01[1], w23[0], w23[1] };
            const bf16x8 pf = __builtin_bit_cast(bf16x8, uu);
            const int sl = ((2 * kt4 + hi) ^ (l32 & 7)) * 8;
            bf16x8 v0 = *reinterpret_cast<const bf16x8*>(&Vs[buf][l32 * 64 + sl]);
            bf16x8 v1 = *reinterpret_cast<const bf16x8*>(&Vs[buf][(32 + l32) * 64 + sl]);
            oacc[0] = __builtin_amdgcn_mfma_f32_32x32x16_bf16(v0, pf, oacc[0], 0, 0, 0);
            oacc[1] = __builtin_amdgcn_mfma_f32_32x32x16_bf16(v1, pf, oacc[1], 0, 0, 0);
        }

        // ---- chunk boundary / advance ----
        if (kt == nkt - 1) {
            storeO(chunk);
            if (t < 40) {
                chunk = 31 - pi;
                nkt   = 36 - pi;
                kt = 0;
                mrow = -1e30f; lrow = 0.f;
                #pragma unroll
                for (int r = 0; r < 16; ++r) { oacc[0][r] = 0.f; oacc[1][r] = 0.f; }
                loadQ(chunk);
            }
        } else {
            ++kt;
        }
        buf ^= 1;
        __syncthreads();   // drains vmcnt(0): next tile's staging is complete
    }
}

// ---------------- out projection: (8192 x 768) @ (768 x 768)^T -> f32 ----------------
__global__ __launch_bounds__(256) void k_out_gemm(
        const unsigned short* __restrict__ A, const unsigned short* __restrict__ W,
        float* __restrict__ out) {
    __shared__ __align__(16) unsigned short As[8192];
    __shared__ __align__(16) unsigned short Bs[8192];
    const int tid  = threadIdx.x;
    const int wave = tid >> 6;
    const int lane = tid & 63;
    const int g = lane >> 4, l16 = lane & 15;
    const int m0 = blockIdx.x * 128, n0 = blockIdx.y * 128;
    const int wr = wave >> 1, wc = wave & 1;

    f32x4 acc[4][4] = {};

    for (int k0 = 0; k0 < Cn; k0 += 64) {
        #pragma unroll
        for (int inst = 0; inst < 4; ++inst) {
            const int li = inst * 256 + tid;
            const int row = li >> 3, slot = li & 7;
            const int ch = slot ^ (row & 7);
            ASYNC16(A + (size_t)(m0 + row) * Cn + k0 + ch * 8,
                    &As[(inst * 256 + wave * 64) * 8]);
            ASYNC16(W + (size_t)(n0 + row) * Cn + k0 + ch * 8,
                    &Bs[(inst * 256 + wave * 64) * 8]);
        }
        __syncthreads();
        #pragma unroll
        for (int kk = 0; kk < 2; ++kk) {
            bf16x8 af[4], bfv[4];
            #pragma unroll
            for (int mt = 0; mt < 4; ++mt) {
                const int row = wr * 64 + mt * 16 + l16;
                const int slot = (kk * 4 + g) ^ (row & 7);
                af[mt] = *reinterpret_cast<const bf16x8*>(&As[row * 64 + slot * 8]);
            }
            #pragma unroll
            for (int nt = 0; nt < 4; ++nt) {
                const int row = wc * 64 + nt * 16 + l16;
                const int slot = (kk * 4 + g) ^ (row & 7);
                bfv[nt] = *reinterpret_cast<const bf16x8*>(&Bs[row * 64 + slot * 8]);
            }
            #pragma unroll
            for (int mt = 0; mt < 4; ++mt)
                #pragma unroll
                for (int nt = 0; nt < 4; ++nt)
                    acc[mt][nt] = __builtin_amdgcn_mfma_f32_16x16x32_bf16(
                            af[mt], bfv[nt], acc[mt][nt], 0, 0, 0);
        }
        __syncthreads();
    }

    #pragma unroll
    for (int mt = 0; mt < 4; ++mt)
        #pragma unroll
        for (int nt = 0; nt < 4; ++nt)
            #pragma unroll
            for (int r = 0; r < 4; ++r) {
                const int m = m0 + wr * 64 + mt * 16 + g * 4 + r;
                const int n = n0 + wc * 64 + nt * 16 + l16;
                out[(size_t)m * Cn + n] = acc[mt][nt][r];
            }
}

extern "C" void kernel_launch(void* const* d_in, const int* in_sizes, int n_in,
                              void* d_out, int out_size, void* d_ws, size_t ws_size,
                              hipStream_t stream) {
    const float* x    = (const float*)d_in[0];
    const float* pre  = (const float*)d_in[1];
    const float* wqkv = (const float*)d_in[2];
    const float* wout = (const float*)d_in[3];
    float* out = (float*)d_out;
    char* ws = (char*)d_ws;

    unsigned short* xf  = (unsigned short*)(ws + 0);          // B*TALL*C bf16
    unsigned short* wqb = (unsigned short*)(ws + 14155776);   // 3C*C bf16
    unsigned short* wob = (unsigned short*)(ws + 17694720);   // C*C bf16
    unsigned short* Qb  = (unsigned short*)(ws + 18874368);   // B,H,TALL,HD (pre-scaled)
    unsigned short* Kb  = (unsigned short*)(ws + 33030144);   // B,H,TALL,HD
    unsigned short* Vt  = (unsigned short*)(ws + 47185920);   // B,H,HD,TALL
    unsigned short* Ob  = (unsigned short*)(ws + 61341696);   // B*T,C bf16

    k_build_xfull<<<dim3((Bn * TALLn * Cn / 4) / 256), 256, 0, stream>>>(x, pre, xf);
    k_cast<<<dim3((3 * Cn * Cn / 4) / 256), 256, 0, stream>>>(wqkv, wqb);
    k_cast<<<dim3((Cn * Cn / 4) / 256), 256, 0, stream>>>(wout, wob);
    k_qkv_gemm<<<dim3((Bn * TALLn) / 128, (3 * Cn) / 128), 256, 0, stream>>>(
            xf, wqb, Qb, Kb, Vt);
    k_attn<<<dim3(768), 128, 0, stream>>>(Qb, Kb, Vt, Ob);
    k_out_gemm<<<dim3((Bn * Tn) / 128, Cn / 128), 256, 0, stream>>>(Ob, wob, out);
}

// Round 4
// 184.771 us; speedup vs baseline: 1.7077x; 1.1143x over previous
//
#include <hip/hip_runtime.h>

// Problem constants
constexpr int Bn   = 4;
constexpr int Tn   = 2048;
constexpr int TPn  = 256;
constexpr int TALLn = 2304;   // TPn + Tn
constexpr int Cn   = 768;
constexpr int Hn   = 12;
constexpr int HDn  = 64;

typedef __bf16 bf16x4 __attribute__((ext_vector_type(4)));
typedef __bf16 bf16x8 __attribute__((ext_vector_type(8)));
typedef float  f32x4  __attribute__((ext_vector_type(4)));
typedef float  f32x16 __attribute__((ext_vector_type(16)));
typedef unsigned u32x4 __attribute__((ext_vector_type(4)));

// RNE float -> bf16 bits (finite inputs only)
__device__ __forceinline__ unsigned short f2bf(float f) {
    unsigned int x = __float_as_uint(f);
    x += 0x7fffu + ((x >> 16) & 1u);
    return (unsigned short)(x >> 16);
}

// packed RNE f32x2 -> bf16x2 (single HW instruction on gfx950)
__device__ __forceinline__ unsigned cvt_pk_bf16(float a, float b) {
    unsigned r;
    asm("v_cvt_pk_bf16_f32 %0, %1, %2" : "=v"(r) : "v"(a), "v"(b));
    return r;
}

// async global->LDS, 16B per lane; lds dst must be wave-uniform base (HW appends lane*16)
#define ASYNC16(gsrc, ldst)                                                           \
    __builtin_amdgcn_global_load_lds((__attribute__((address_space(1))) void*)(gsrc), \
                                     (__attribute__((address_space(3))) void*)(ldst), \
                                     16, 0, 0)

// ---------------- cast kernels ----------------
__global__ __launch_bounds__(256) void k_build_xfull(
        const float* __restrict__ x, const float* __restrict__ pre,
        unsigned short* __restrict__ xf) {
    int idx = blockIdx.x * 256 + threadIdx.x;           // one float4 per thread
    int row = idx / (Cn / 4);                           // token row in (B*TALL)
    int c   = (idx - row * (Cn / 4)) * 4;
    int b = row / TALLn, tt = row - b * TALLn;
    const float* src = (tt < TPn) ? pre + ((size_t)b * TPn + tt) * Cn + c
                                  : x   + ((size_t)b * Tn + (tt - TPn)) * Cn + c;
    float4 f = *reinterpret_cast<const float4*>(src);
    ushort4 o = { f2bf(f.x), f2bf(f.y), f2bf(f.z), f2bf(f.w) };
    *reinterpret_cast<ushort4*>(xf + (size_t)row * Cn + c) = o;
}

__global__ __launch_bounds__(256) void k_cast(
        const float* __restrict__ in, unsigned short* __restrict__ out) {
    int idx = (blockIdx.x * 256 + threadIdx.x) * 4;
    float4 f = *reinterpret_cast<const float4*>(in + idx);
    ushort4 o = { f2bf(f.x), f2bf(f.y), f2bf(f.z), f2bf(f.w) };
    *reinterpret_cast<ushort4*>(out + idx) = o;
}

// ---------------- QKV GEMM: (9216 x 768) @ (2304 x 768)^T ----------------
// 128x128 tile, BK=64, 4 waves (2x2), wave computes 64x64 via 4x4 16x16x32 MFMAs.
// LDS rows are 64 shorts (128B); slot(chunk) swizzle: slot = chunk ^ (row&7).
// Q output is pre-scaled by (1/8)*log2(e) so attention softmax runs in exp2 domain.
__global__ __launch_bounds__(256) void k_qkv_gemm(
        const unsigned short* __restrict__ A, const unsigned short* __restrict__ W,
        unsigned short* __restrict__ Qb, unsigned short* __restrict__ Kb,
        unsigned short* __restrict__ Vt) {
    __shared__ __align__(16) unsigned short smem[16384];   // A:0..8191, B:8192..16383
    unsigned short* As = smem;
    unsigned short* Bs = smem + 8192;
    const int tid  = threadIdx.x;
    const int wave = tid >> 6;
    const int lane = tid & 63;
    const int g = lane >> 4, l16 = lane & 15;
    const int m0 = blockIdx.x * 128, n0 = blockIdx.y * 128;
    const int wr = wave >> 1, wc = wave & 1;

    f32x4 acc[4][4] = {};

    for (int k0 = 0; k0 < Cn; k0 += 64) {
        #pragma unroll
        for (int inst = 0; inst < 4; ++inst) {
            const int li = inst * 256 + tid;            // [0,1024)
            const int row = li >> 3, slot = li & 7;
            const int ch = slot ^ (row & 7);            // inverse-swizzled source
            ASYNC16(A + (size_t)(m0 + row) * Cn + k0 + ch * 8,
                    &As[(inst * 256 + wave * 64) * 8]);
            ASYNC16(W + (size_t)(n0 + row) * Cn + k0 + ch * 8,
                    &Bs[(inst * 256 + wave * 64) * 8]);
        }
        __syncthreads();
        #pragma unroll
        for (int kk = 0; kk < 2; ++kk) {
            bf16x8 af[4], bfv[4];
            #pragma unroll
            for (int mt = 0; mt < 4; ++mt) {
                const int row = wr * 64 + mt * 16 + l16;
                const int slot = (kk * 4 + g) ^ (row & 7);
                af[mt] = *reinterpret_cast<const bf16x8*>(&As[row * 64 + slot * 8]);
            }
            #pragma unroll
            for (int nt = 0; nt < 4; ++nt) {
                const int row = wc * 64 + nt * 16 + l16;
                const int slot = (kk * 4 + g) ^ (row & 7);
                bfv[nt] = *reinterpret_cast<const bf16x8*>(&Bs[row * 64 + slot * 8]);
            }
            #pragma unroll
            for (int mt = 0; mt < 4; ++mt)
                #pragma unroll
                for (int nt = 0; nt < 4; ++nt)
                    acc[mt][nt] = __builtin_amdgcn_mfma_f32_16x16x32_bf16(
                            af[mt], bfv[nt], acc[mt][nt], 0, 0, 0);
        }
        __syncthreads();
    }

    // epilogue
    const int b   = m0 / TALLn;        // 2304 % 128 == 0
    const int t0  = m0 - b * TALLn;
    const int sel = n0 / Cn;           // 768 % 128 == 0
    const int hn0 = n0 - sel * Cn;
    constexpr float SCQ = 0.18033688011112042f;   // (1/8) * log2(e)

    if (sel == 2) {
        // V: transpose 128x128 tile via LDS, then coalesced 16B stores to V^T.
        #pragma unroll
        for (int mt = 0; mt < 4; ++mt)
            #pragma unroll
            for (int nt = 0; nt < 4; ++nt)
                #pragma unroll
                for (int r = 0; r < 4; ++r) {
                    const int t  = wr * 64 + mt * 16 + g * 4 + r;
                    const int hn = wc * 64 + nt * 16 + l16;
                    smem[hn * 128 + (((t >> 3) ^ (hn & 7)) << 3) + (t & 7)] =
                            f2bf(acc[mt][nt][r]);
                }
        __syncthreads();
        #pragma unroll
        for (int j = 0; j < 8; ++j) {
            const int u  = tid + 256 * j;
            const int hn = u >> 4, tc = u & 15;
            bf16x8 v = *reinterpret_cast<const bf16x8*>(
                    &smem[hn * 128 + ((tc ^ (hn & 7)) << 3)]);
            const int hh = (hn0 + hn) >> 6;
            const int dd = hn & 63;
            *reinterpret_cast<bf16x8*>(
                    &Vt[(((size_t)b * Hn + hh) * HDn + dd) * TALLn + t0 + tc * 8]) = v;
        }
    } else {
        #pragma unroll
        for (int mt = 0; mt < 4; ++mt)
            #pragma unroll
            for (int nt = 0; nt < 4; ++nt)
                #pragma unroll
                for (int r = 0; r < 4; ++r) {
                    const int t  = t0 + wr * 64 + mt * 16 + g * 4 + r;
                    const int hn = hn0 + wc * 64 + nt * 16 + l16;
                    const int h = hn >> 6, d = hn & 63;
                    if (sel == 0)
                        Qb[(((size_t)b * Hn + h) * TALLn + t) * HDn + d] =
                                f2bf(acc[mt][nt][r] * SCQ);
                    else
                        Kb[(((size_t)b * Hn + h) * TALLn + t) * HDn + d] =
                                f2bf(acc[mt][nt][r]);
                }
    }
}

// ---------------- flash attention over x-rows (swapped 32x32, zero-shuffle PV) ------
// 768 blocks of 128 threads (2 waves x 32 q rows = 64-q chunk), chunk pair (pi,31-pi)
// -> 41 K-tiles per block. XCD swizzle groups same-(b,h) blocks per XCD.
// S^T = mfma32x32(K, Q): q = lane&31 lane-local. PV key order is permuted per 16-key
// band so the C-layout (+4*hi) directly supplies the B-layout (8*hi) -> no shuffles.
__global__ __launch_bounds__(128) void k_attn(
        const unsigned short* __restrict__ Qb, const unsigned short* __restrict__ Kb,
        const unsigned short* __restrict__ Vt, unsigned short* __restrict__ Ob) {
    __shared__ __align__(16) unsigned short Ks[2][4096];
    __shared__ __align__(16) unsigned short Vs[2][4096];
    const int tid  = threadIdx.x;
    const int wave = tid >> 6;
    const int lane = tid & 63;
    const int l32  = lane & 31;
    const int hi   = lane >> 5;
    const int hi4  = hi * 4;

    // XCD swizzle: consecutive HW blocks round-robin XCDs; give each XCD 6 whole bh.
    const int fb = blockIdx.x;            // 0..767
    const int j  = fb >> 3;
    const int bh = 6 * (fb & 7) + (j >> 4);
    const int pi = j & 15;
    const size_t kv = (size_t)bh * TALLn * HDn;

    // hoisted LDS read offsets (shorts), loop-invariant
    int koff[4], voff0[4], voff1[4];
    #pragma unroll
    for (int s = 0; s < 4; ++s)
        koff[s] = l32 * 64 + (((2 * s + hi) ^ (l32 & 7)) << 3);
    #pragma unroll
    for (int band = 0; band < 4; ++band) {
        voff0[band] = l32 * 64 + (((2 * band)     ^ (l32 & 7)) << 3) + hi4;
        voff1[band] = l32 * 64 + (((2 * band + 1) ^ (l32 & 7)) << 3) + hi4;
    }
    // hoisted staging source offsets (shorts)
    int soffK[4], soffV[4], sdst[4];
    #pragma unroll
    for (int inst = 0; inst < 4; ++inst) {
        const int li = inst * 128 + tid;       // [0,512)
        const int row = li >> 3;
        const int ch = (li & 7) ^ (row & 7);   // pre-swizzled global source
        soffK[inst] = row * HDn + ch * 8;
        soffV[inst] = row * TALLn + ch * 8;
        sdst[inst]  = (inst * 128 + wave * 64) * 8;
    }

    bf16x8 qf[4];
    auto loadQ = [&](int ch) {
        const int tq = TPn + ch * 64 + wave * 32 + l32;
        #pragma unroll
        for (int s = 0; s < 4; ++s)
            qf[s] = *reinterpret_cast<const bf16x8*>(
                    Qb + kv + (size_t)tq * HDn + s * 16 + hi * 8);
    };
    auto stageKV = [&](int bs, int kt0) {
        unsigned short* kb = &Ks[bs][0];
        unsigned short* vb = &Vs[bs][0];
        const unsigned short* gk = Kb + kv + (size_t)kt0 * HDn;
        const unsigned short* gv = Vt + kv + kt0;
        #pragma unroll
        for (int inst = 0; inst < 4; ++inst) {
            ASYNC16(gk + soffK[inst], kb + sdst[inst]);
            ASYNC16(gv + soffV[inst], vb + sdst[inst]);
        }
    };

    f32x16 oacc[2] = {};
    float mrow = -1e30f, lrow = 0.f;

    const int b = bh / Hn, h = bh - b * Hn;
    auto storeO = [&](int ch) {
        const float inv = 1.0f / lrow;
        const size_t row = (size_t)b * Tn + ch * 64 + wave * 32 + l32;
        #pragma unroll
        for (int dt = 0; dt < 2; ++dt)
            #pragma unroll
            for (int t4 = 0; t4 < 4; ++t4) {
                ushort4 st;
                st.x = f2bf(oacc[dt][4 * t4 + 0] * inv);
                st.y = f2bf(oacc[dt][4 * t4 + 1] * inv);
                st.z = f2bf(oacc[dt][4 * t4 + 2] * inv);
                st.w = f2bf(oacc[dt][4 * t4 + 3] * inv);
                const int d0 = dt * 32 + 4 * hi + 8 * t4;
                *reinterpret_cast<ushort4*>(&Ob[row * Cn + h * 64 + d0]) = st;
            }
    };

    int chunk = pi;
    int nkt   = 5 + pi;
    int kt = 0, buf = 0;
    loadQ(chunk);
    stageKV(0, 0);
    __syncthreads();

    for (int t = 0; t < 41; ++t) {
        if (t < 40) {                       // prefetch next tile (wraps to chunk B)
            const int nk0 = (kt + 1 < nkt) ? (kt + 1) * 64 : 0;
            stageKV(buf ^ 1, nk0);
        }
        const unsigned short* Ksb = &Ks[buf][0];
        const unsigned short* Vsb = &Vs[buf][0];

        // ---- S^T = K * Q over 64 keys (two 32-key tiles), k = 64 dims ----
        f32x16 s0 = {}, s1 = {};
        #pragma unroll
        for (int s = 0; s < 4; ++s) {
            bf16x8 k0 = *reinterpret_cast<const bf16x8*>(&Ksb[koff[s]]);
            bf16x8 k1 = *reinterpret_cast<const bf16x8*>(&Ksb[2048 + koff[s]]);
            s0 = __builtin_amdgcn_mfma_f32_32x32x16_bf16(k0, qf[s], s0, 0, 0, 0);
            s1 = __builtin_amdgcn_mfma_f32_32x32x16_bf16(k1, qf[s], s1, 0, 0, 0);
        }

        // ---- online softmax (q = l32 lane-local; 32 key-values in-lane) ----
        if (kt == nkt - 1) {                // mask only the diagonal tile
            const int lim = TPn + chunk * 64 + wave * 32 + l32 - kt * 64;
            #pragma unroll
            for (int r = 0; r < 16; ++r) {
                const int ro = (r & 3) + 8 * (r >> 2) + hi4;
                s0[r] = (ro <= lim)      ? s0[r] : -1e30f;
                s1[r] = (32 + ro <= lim) ? s1[r] : -1e30f;
            }
        }
        float pm = fmaxf(s0[0], s1[0]);
        #pragma unroll
        for (int r = 1; r < 16; ++r) pm = fmaxf(pm, fmaxf(s0[r], s1[r]));
        pm = fmaxf(pm, __shfl_xor(pm, 32));

        if (!__all(pm <= mrow)) {           // defer-max: exact (THR=0)
            const float mnew  = fmaxf(mrow, pm);
            const float alpha = exp2f(mrow - mnew);
            mrow = mnew;
            lrow *= alpha;
            oacc[0] *= alpha;
            oacc[1] *= alpha;
        }

        float rsa = 0.f, rsb = 0.f;
        unsigned dw[2][8];
        #pragma unroll
        for (int i = 0; i < 8; ++i) {
            const float a0 = exp2f(s0[2 * i] - mrow);
            const float a1 = exp2f(s0[2 * i + 1] - mrow);
            const float b0 = exp2f(s1[2 * i] - mrow);
            const float b1 = exp2f(s1[2 * i + 1] - mrow);
            rsa += a0 + a1;
            rsb += b0 + b1;
            dw[0][i] = cvt_pk_bf16(a0, a1);
            dw[1][i] = cvt_pk_bf16(b0, b1);
        }
        float rs = rsa + rsb;
        rs += __shfl_xor(rs, 32);
        lrow += rs;

        // ---- O^T += V^T * P^T : zero-shuffle, key order permuted per band ----
        #pragma unroll
        for (int band = 0; band < 4; ++band) {
            const int tt = band >> 1, c0 = 4 * (band & 1);
            const u32x4 uu = { dw[tt][c0 + 0], dw[tt][c0 + 1],
                               dw[tt][c0 + 2], dw[tt][c0 + 3] };
            const bf16x8 pf = __builtin_bit_cast(bf16x8, uu);
            bf16x4 a00 = *reinterpret_cast<const bf16x4*>(&Vsb[voff0[band]]);
            bf16x4 a01 = *reinterpret_cast<const bf16x4*>(&Vsb[voff1[band]]);
            bf16x4 a10 = *reinterpret_cast<const bf16x4*>(&Vsb[2048 + voff0[band]]);
            bf16x4 a11 = *reinterpret_cast<const bf16x4*>(&Vsb[2048 + voff1[band]]);
            bf16x8 v0 = __builtin_shufflevector(a00, a01, 0, 1, 2, 3, 4, 5, 6, 7);
            bf16x8 v1 = __builtin_shufflevector(a10, a11, 0, 1, 2, 3, 4, 5, 6, 7);
            oacc[0] = __builtin_amdgcn_mfma_f32_32x32x16_bf16(v0, pf, oacc[0], 0, 0, 0);
            oacc[1] = __builtin_amdgcn_mfma_f32_32x32x16_bf16(v1, pf, oacc[1], 0, 0, 0);
        }

        // ---- chunk boundary / advance ----
        if (kt == nkt - 1) {
            storeO(chunk);
            if (t < 40) {
                chunk = 31 - pi;
                nkt   = 36 - pi;
                kt = 0;
                mrow = -1e30f; lrow = 0.f;
                #pragma unroll
                for (int r = 0; r < 16; ++r) { oacc[0][r] = 0.f; oacc[1][r] = 0.f; }
                loadQ(chunk);
            }
        } else {
            ++kt;
        }
        buf ^= 1;
        __syncthreads();   // drains vmcnt(0): next tile's staging is complete
    }
}

// ---------------- out projection: (8192 x 768) @ (768 x 768)^T -> f32 ----------------
__global__ __launch_bounds__(256) void k_out_gemm(
        const unsigned short* __restrict__ A, const unsigned short* __restrict__ W,
        float* __restrict__ out) {
    __shared__ __align__(16) unsigned short As[8192];
    __shared__ __align__(16) unsigned short Bs[8192];
    const int tid  = threadIdx.x;
    const int wave = tid >> 6;
    const int lane = tid & 63;
    const int g = lane >> 4, l16 = lane & 15;
    const int m0 = blockIdx.x * 128, n0 = blockIdx.y * 128;
    const int wr = wave >> 1, wc = wave & 1;

    f32x4 acc[4][4] = {};

    for (int k0 = 0; k0 < Cn; k0 += 64) {
        #pragma unroll
        for (int inst = 0; inst < 4; ++inst) {
            const int li = inst * 256 + tid;
            const int row = li >> 3, slot = li & 7;
            const int ch = slot ^ (row & 7);
            ASYNC16(A + (size_t)(m0 + row) * Cn + k0 + ch * 8,
                    &As[(inst * 256 + wave * 64) * 8]);
            ASYNC16(W + (size_t)(n0 + row) * Cn + k0 + ch * 8,
                    &Bs[(inst * 256 + wave * 64) * 8]);
        }
        __syncthreads();
        #pragma unroll
        for (int kk = 0; kk < 2; ++kk) {
            bf16x8 af[4], bfv[4];
            #pragma unroll
            for (int mt = 0; mt < 4; ++mt) {
                const int row = wr * 64 + mt * 16 + l16;
                const int slot = (kk * 4 + g) ^ (row & 7);
                af[mt] = *reinterpret_cast<const bf16x8*>(&As[row * 64 + slot * 8]);
            }
            #pragma unroll
            for (int nt = 0; nt < 4; ++nt) {
                const int row = wc * 64 + nt * 16 + l16;
                const int slot = (kk * 4 + g) ^ (row & 7);
                bfv[nt] = *reinterpret_cast<const bf16x8*>(&Bs[row * 64 + slot * 8]);
            }
            #pragma unroll
            for (int mt = 0; mt < 4; ++mt)
                #pragma unroll
                for (int nt = 0; nt < 4; ++nt)
                    acc[mt][nt] = __builtin_amdgcn_mfma_f32_16x16x32_bf16(
                            af[mt], bfv[nt], acc[mt][nt], 0, 0, 0);
        }
        __syncthreads();
    }

    #pragma unroll
    for (int mt = 0; mt < 4; ++mt)
        #pragma unroll
        for (int nt = 0; nt < 4; ++nt)
            #pragma unroll
            for (int r = 0; r < 4; ++r) {
                const int m = m0 + wr * 64 + mt * 16 + g * 4 + r;
                const int n = n0 + wc * 64 + nt * 16 + l16;
                out[(size_t)m * Cn + n] = acc[mt][nt][r];
            }
}

extern "C" void kernel_launch(void* const* d_in, const int* in_sizes, int n_in,
                              void* d_out, int out_size, void* d_ws, size_t ws_size,
                              hipStream_t stream) {
    const float* x    = (const float*)d_in[0];
    const float* pre  = (const float*)d_in[1];
    const float* wqkv = (const float*)d_in[2];
    const float* wout = (const float*)d_in[3];
    float* out = (float*)d_out;
    char* ws = (char*)d_ws;

    unsigned short* xf  = (unsigned short*)(ws + 0);          // B*TALL*C bf16
    unsigned short* wqb = (unsigned short*)(ws + 14155776);   // 3C*C bf16
    unsigned short* wob = (unsigned short*)(ws + 17694720);   // C*C bf16
    unsigned short* Qb  = (unsigned short*)(ws + 18874368);   // B,H,TALL,HD (pre-scaled)
    unsigned short* Kb  = (unsigned short*)(ws + 33030144);   // B,H,TALL,HD
    unsigned short* Vt  = (unsigned short*)(ws + 47185920);   // B,H,HD,TALL
    unsigned short* Ob  = (unsigned short*)(ws + 61341696);   // B*T,C bf16

    k_build_xfull<<<dim3((Bn * TALLn * Cn / 4) / 256), 256, 0, stream>>>(x, pre, xf);
    k_cast<<<dim3((3 * Cn * Cn / 4) / 256), 256, 0, stream>>>(wqkv, wqb);
    k_cast<<<dim3((Cn * Cn / 4) / 256), 256, 0, stream>>>(wout, wob);
    k_qkv_gemm<<<dim3((Bn * TALLn) / 128, (3 * Cn) / 128), 256, 0, stream>>>(
            xf, wqb, Qb, Kb, Vt);
    k_attn<<<dim3(768), 128, 0, stream>>>(Qb, Kb, Vt, Ob);
    k_out_gemm<<<dim3((Bn * Tn) / 128, Cn / 128), 256, 0, stream>>>(Ob, wob, out);
}

// Round 5
// 168.204 us; speedup vs baseline: 1.8759x; 1.0985x over previous
//
#include <hip/hip_runtime.h>

// Problem constants
constexpr int Bn   = 4;
constexpr int Tn   = 2048;
constexpr int TPn  = 256;
constexpr int TALLn = 2304;   // TPn + Tn
constexpr int Cn   = 768;
constexpr int Hn   = 12;
constexpr int HDn  = 64;

typedef __bf16 bf16x4 __attribute__((ext_vector_type(4)));
typedef __bf16 bf16x8 __attribute__((ext_vector_type(8)));
typedef float  f32x4  __attribute__((ext_vector_type(4)));
typedef unsigned u32x4 __attribute__((ext_vector_type(4)));

// RNE float -> bf16 bits (finite inputs only)
__device__ __forceinline__ unsigned short f2bf(float f) {
    unsigned int x = __float_as_uint(f);
    x += 0x7fffu + ((x >> 16) & 1u);
    return (unsigned short)(x >> 16);
}

// packed RNE f32x2 -> bf16x2 (single HW instruction on gfx950)
__device__ __forceinline__ unsigned cvt_pk_bf16(float a, float b) {
    unsigned r;
    asm("v_cvt_pk_bf16_f32 %0, %1, %2" : "=v"(r) : "v"(a), "v"(b));
    return r;
}

// async global->LDS, 16B per lane; lds dst must be wave-uniform base (HW appends lane*16)
#define ASYNC16(gsrc, ldst)                                                           \
    __builtin_amdgcn_global_load_lds((__attribute__((address_space(1))) void*)(gsrc), \
                                     (__attribute__((address_space(3))) void*)(ldst), \
                                     16, 0, 0)

// ---------------- cast kernels ----------------
__global__ __launch_bounds__(256) void k_build_xfull(
        const float* __restrict__ x, const float* __restrict__ pre,
        unsigned short* __restrict__ xf) {
    int idx = blockIdx.x * 256 + threadIdx.x;           // one float4 per thread
    int row = idx / (Cn / 4);                           // token row in (B*TALL)
    int c   = (idx - row * (Cn / 4)) * 4;
    int b = row / TALLn, tt = row - b * TALLn;
    const float* src = (tt < TPn) ? pre + ((size_t)b * TPn + tt) * Cn + c
                                  : x   + ((size_t)b * Tn + (tt - TPn)) * Cn + c;
    float4 f = *reinterpret_cast<const float4*>(src);
    ushort4 o = { f2bf(f.x), f2bf(f.y), f2bf(f.z), f2bf(f.w) };
    *reinterpret_cast<ushort4*>(xf + (size_t)row * Cn + c) = o;
}

__global__ __launch_bounds__(256) void k_cast(
        const float* __restrict__ in, unsigned short* __restrict__ out) {
    int idx = (blockIdx.x * 256 + threadIdx.x) * 4;
    float4 f = *reinterpret_cast<const float4*>(in + idx);
    ushort4 o = { f2bf(f.x), f2bf(f.y), f2bf(f.z), f2bf(f.w) };
    *reinterpret_cast<ushort4*>(out + idx) = o;
}

// ---------------- QKV GEMM: (9216 x 768) @ (2304 x 768)^T ----------------
// 128x128 tile, BK=64, 4 waves (2x2), wave computes 64x64 via 4x4 16x16x32 MFMAs.
// LDS rows are 64 shorts (128B); slot(chunk) swizzle: slot = chunk ^ (row&7).
// Q output is pre-scaled by (1/8)*log2(e) so attention softmax runs in exp2 domain.
__global__ __launch_bounds__(256) void k_qkv_gemm(
        const unsigned short* __restrict__ A, const unsigned short* __restrict__ W,
        unsigned short* __restrict__ Qb, unsigned short* __restrict__ Kb,
        unsigned short* __restrict__ Vt) {
    __shared__ __align__(16) unsigned short smem[16384];   // A:0..8191, B:8192..16383
    unsigned short* As = smem;
    unsigned short* Bs = smem + 8192;
    const int tid  = threadIdx.x;
    const int wave = tid >> 6;
    const int lane = tid & 63;
    const int g = lane >> 4, l16 = lane & 15;
    const int m0 = blockIdx.x * 128, n0 = blockIdx.y * 128;
    const int wr = wave >> 1, wc = wave & 1;

    f32x4 acc[4][4] = {};

    for (int k0 = 0; k0 < Cn; k0 += 64) {
        #pragma unroll
        for (int inst = 0; inst < 4; ++inst) {
            const int li = inst * 256 + tid;            // [0,1024)
            const int row = li >> 3, slot = li & 7;
            const int ch = slot ^ (row & 7);            // inverse-swizzled source
            ASYNC16(A + (size_t)(m0 + row) * Cn + k0 + ch * 8,
                    &As[(inst * 256 + wave * 64) * 8]);
            ASYNC16(W + (size_t)(n0 + row) * Cn + k0 + ch * 8,
                    &Bs[(inst * 256 + wave * 64) * 8]);
        }
        __syncthreads();
        #pragma unroll
        for (int kk = 0; kk < 2; ++kk) {
            bf16x8 af[4], bfv[4];
            #pragma unroll
            for (int mt = 0; mt < 4; ++mt) {
                const int row = wr * 64 + mt * 16 + l16;
                const int slot = (kk * 4 + g) ^ (row & 7);
                af[mt] = *reinterpret_cast<const bf16x8*>(&As[row * 64 + slot * 8]);
            }
            #pragma unroll
            for (int nt = 0; nt < 4; ++nt) {
                const int row = wc * 64 + nt * 16 + l16;
                const int slot = (kk * 4 + g) ^ (row & 7);
                bfv[nt] = *reinterpret_cast<const bf16x8*>(&Bs[row * 64 + slot * 8]);
            }
            #pragma unroll
            for (int mt = 0; mt < 4; ++mt)
                #pragma unroll
                for (int nt = 0; nt < 4; ++nt)
                    acc[mt][nt] = __builtin_amdgcn_mfma_f32_16x16x32_bf16(
                            af[mt], bfv[nt], acc[mt][nt], 0, 0, 0);
        }
        __syncthreads();
    }

    // epilogue
    const int b   = m0 / TALLn;        // 2304 % 128 == 0
    const int t0  = m0 - b * TALLn;
    const int sel = n0 / Cn;           // 768 % 128 == 0
    const int hn0 = n0 - sel * Cn;
    constexpr float SCQ = 0.18033688011112042f;   // (1/8) * log2(e)

    if (sel == 2) {
        // V: transpose 128x128 tile via LDS, then coalesced 16B stores to V^T.
        #pragma unroll
        for (int mt = 0; mt < 4; ++mt)
            #pragma unroll
            for (int nt = 0; nt < 4; ++nt)
                #pragma unroll
                for (int r = 0; r < 4; ++r) {
                    const int t  = wr * 64 + mt * 16 + g * 4 + r;
                    const int hn = wc * 64 + nt * 16 + l16;
                    smem[hn * 128 + (((t >> 3) ^ (hn & 7)) << 3) + (t & 7)] =
                            f2bf(acc[mt][nt][r]);
                }
        __syncthreads();
        #pragma unroll
        for (int j = 0; j < 8; ++j) {
            const int u  = tid + 256 * j;
            const int hn = u >> 4, tc = u & 15;
            bf16x8 v = *reinterpret_cast<const bf16x8*>(
                    &smem[hn * 128 + ((tc ^ (hn & 7)) << 3)]);
            const int hh = (hn0 + hn) >> 6;
            const int dd = hn & 63;
            *reinterpret_cast<bf16x8*>(
                    &Vt[(((size_t)b * Hn + hh) * HDn + dd) * TALLn + t0 + tc * 8]) = v;
        }
    } else {
        #pragma unroll
        for (int mt = 0; mt < 4; ++mt)
            #pragma unroll
            for (int nt = 0; nt < 4; ++nt)
                #pragma unroll
                for (int r = 0; r < 4; ++r) {
                    const int t  = t0 + wr * 64 + mt * 16 + g * 4 + r;
                    const int hn = hn0 + wc * 64 + nt * 16 + l16;
                    const int h = hn >> 6, d = hn & 63;
                    if (sel == 0)
                        Qb[(((size_t)b * Hn + h) * TALLn + t) * HDn + d] =
                                f2bf(acc[mt][nt][r] * SCQ);
                    else
                        Kb[(((size_t)b * Hn + h) * TALLn + t) * HDn + d] =
                                f2bf(acc[mt][nt][r]);
                }
    }
}

// ---------------- flash attention over x-rows (16q waves, 4 waves/block) ------------
// 768 blocks of 256 threads: 4 waves x 16 q rows = 64-q chunk; chunk pair (pi,31-pi)
// -> 41 K-tiles per block, even. 3072 waves total -> ~12 waves/CU.
// S^T = mfma16x16x32(K, Q): q = lane&15 lane-local; lane (g) holds keys band*16+g*4+r.
// PV key order permuted per band: C-layout keys g*4+r feed B k-slots g*8+j directly.
__global__ __launch_bounds__(256) void k_attn(
        const unsigned short* __restrict__ Qb, const unsigned short* __restrict__ Kb,
        const unsigned short* __restrict__ Vt, unsigned short* __restrict__ Ob) {
    __shared__ __align__(16) unsigned short Ks[2][4096];
    __shared__ __align__(16) unsigned short Vs[2][4096];
    const int tid  = threadIdx.x;
    const int wq   = tid >> 6;             // wave owns q rows [wq*16, wq*16+16)
    const int lane = tid & 63;
    const int l16  = lane & 15;
    const int g    = lane >> 4;            // 0..3

    // XCD swizzle: consecutive HW blocks round-robin XCDs; give each XCD 6 whole bh.
    const int fb = blockIdx.x;             // 0..767
    const int j  = fb >> 3;
    const int bh = 6 * (fb & 7) + (j >> 4);
    const int pi = j & 15;
    const size_t kv = (size_t)bh * TALLn * HDn;

    // hoisted K-read offsets (shorts): row = band*16+l16, granule (ks*4+g)^(l16&7)
    int koff[4][2];
    #pragma unroll
    for (int band = 0; band < 4; ++band)
        #pragma unroll
        for (int ks = 0; ks < 2; ++ks)
            koff[band][ks] = (band * 16 + l16) * 64 + (((ks * 4 + g) ^ (l16 & 7)) << 3);
    // hoisted V-read offsets (shorts): bf16x4 pairs per kg; row term added per dband
    int voffA[2], voffB[2];
    #pragma unroll
    for (int kg = 0; kg < 2; ++kg) {
        voffA[kg] = l16 * 64 + (((4 * kg + (g >> 1)) ^ (l16 & 7)) << 3) + (g & 1) * 4;
        voffB[kg] = l16 * 64 + (((4 * kg + 2 + (g >> 1)) ^ (l16 & 7)) << 3) + (g & 1) * 4;
    }
    // hoisted staging source offsets (shorts)
    int soffK[2], soffV[2], sdst[2];
    #pragma unroll
    for (int inst = 0; inst < 2; ++inst) {
        const int li = inst * 256 + tid;       // [0,512)
        const int row = li >> 3;
        const int ch = (li & 7) ^ (row & 7);   // pre-swizzled global source
        soffK[inst] = row * HDn + ch * 8;
        soffV[inst] = row * TALLn + ch * 8;
        sdst[inst]  = (inst * 256 + wq * 64) * 8;
    }

    bf16x8 qf[2];
    auto loadQ = [&](int ch) {
        const int tq = TPn + ch * 64 + wq * 16 + l16;
        #pragma unroll
        for (int ks = 0; ks < 2; ++ks)
            qf[ks] = *reinterpret_cast<const bf16x8*>(
                    Qb + kv + (size_t)tq * HDn + ks * 32 + g * 8);
    };
    auto stageKV = [&](int bs, int kt0) {
        unsigned short* kb = &Ks[bs][0];
        unsigned short* vb = &Vs[bs][0];
        const unsigned short* gk = Kb + kv + (size_t)kt0 * HDn;
        const unsigned short* gv = Vt + kv + kt0;
        #pragma unroll
        for (int inst = 0; inst < 2; ++inst) {
            ASYNC16(gk + soffK[inst], kb + sdst[inst]);
            ASYNC16(gv + soffV[inst], vb + sdst[inst]);
        }
    };

    f32x4 oacc[4] = {};                    // O^T: dband*16 + g*4 + r rows, q = l16
    float mrow = -1e30f, lrow = 0.f;

    const int b = bh / Hn, h = bh - b * Hn;
    auto storeO = [&](int ch) {
        const float inv = 1.0f / lrow;
        const size_t row = (size_t)b * Tn + ch * 64 + wq * 16 + l16;
        #pragma unroll
        for (int dband = 0; dband < 4; ++dband) {
            ushort4 st;
            st.x = f2bf(oacc[dband][0] * inv);
            st.y = f2bf(oacc[dband][1] * inv);
            st.z = f2bf(oacc[dband][2] * inv);
            st.w = f2bf(oacc[dband][3] * inv);
            *reinterpret_cast<ushort4*>(
                    &Ob[row * Cn + h * 64 + dband * 16 + g * 4]) = st;
        }
    };

    int chunk = pi;
    int nkt   = 5 + pi;
    int kt = 0, buf = 0;
    loadQ(chunk);
    stageKV(0, 0);
    __syncthreads();

    for (int t = 0; t < 41; ++t) {
        if (t < 40) {                       // prefetch next tile (wraps to chunk B)
            const int nk0 = (kt + 1 < nkt) ? (kt + 1) * 64 : 0;
            stageKV(buf ^ 1, nk0);
        }
        const unsigned short* Ksb = &Ks[buf][0];
        const unsigned short* Vsb = &Vs[buf][0];

        // ---- S^T = K * Q : 4 bands of 16 keys, k = 64 dims (2 steps) ----
        f32x4 sacc[4] = {};
        __builtin_amdgcn_s_setprio(1);
        #pragma unroll
        for (int band = 0; band < 4; ++band) {
            bf16x8 k0 = *reinterpret_cast<const bf16x8*>(&Ksb[koff[band][0]]);
            bf16x8 k1 = *reinterpret_cast<const bf16x8*>(&Ksb[koff[band][1]]);
            sacc[band] = __builtin_amdgcn_mfma_f32_16x16x32_bf16(
                    k0, qf[0], sacc[band], 0, 0, 0);
            sacc[band] = __builtin_amdgcn_mfma_f32_16x16x32_bf16(
                    k1, qf[1], sacc[band], 0, 0, 0);
        }
        __builtin_amdgcn_s_setprio(0);

        // ---- online softmax (q = l16 lane-local; 16 key-values in-lane) ----
        if (kt == nkt - 1) {                // mask only the diagonal tile
            const int lim = TPn + chunk * 64 + wq * 16 + l16 - kt * 64;
            #pragma unroll
            for (int band = 0; band < 4; ++band)
                #pragma unroll
                for (int r = 0; r < 4; ++r)
                    sacc[band][r] = (band * 16 + g * 4 + r <= lim) ? sacc[band][r]
                                                                   : -1e30f;
        }
        float pm = fmaxf(fmaxf(sacc[0][0], sacc[0][1]), fmaxf(sacc[0][2], sacc[0][3]));
        #pragma unroll
        for (int band = 1; band < 4; ++band) {
            pm = fmaxf(pm, fmaxf(fmaxf(sacc[band][0], sacc[band][1]),
                                 fmaxf(sacc[band][2], sacc[band][3])));
        }
        pm = fmaxf(pm, __shfl_xor(pm, 16));
        pm = fmaxf(pm, __shfl_xor(pm, 32));

        if (!__all(pm <= mrow)) {           // defer-max: exact (THR=0)
            const float mnew  = fmaxf(mrow, pm);
            const float alpha = exp2f(mrow - mnew);
            mrow = mnew;
            lrow *= alpha;
            oacc[0] *= alpha;
            oacc[1] *= alpha;
            oacc[2] *= alpha;
            oacc[3] *= alpha;
        }

        float rs = 0.f;
        unsigned dwb[4][2];
        #pragma unroll
        for (int band = 0; band < 4; ++band) {
            const float e0 = exp2f(sacc[band][0] - mrow);
            const float e1 = exp2f(sacc[band][1] - mrow);
            const float e2 = exp2f(sacc[band][2] - mrow);
            const float e3 = exp2f(sacc[band][3] - mrow);
            rs += (e0 + e1) + (e2 + e3);
            dwb[band][0] = cvt_pk_bf16(e0, e1);
            dwb[band][1] = cvt_pk_bf16(e2, e3);
        }
        rs += __shfl_xor(rs, 16);
        rs += __shfl_xor(rs, 32);
        lrow += rs;

        // ---- O^T += V^T * P^T : zero-shuffle, key order permuted per band ----
        __builtin_amdgcn_s_setprio(1);
        #pragma unroll
        for (int kg = 0; kg < 2; ++kg) {
            const u32x4 uu = { dwb[2 * kg][0], dwb[2 * kg][1],
                               dwb[2 * kg + 1][0], dwb[2 * kg + 1][1] };
            const bf16x8 pf = __builtin_bit_cast(bf16x8, uu);
            #pragma unroll
            for (int dband = 0; dband < 4; ++dband) {
                bf16x4 a0 = *reinterpret_cast<const bf16x4*>(
                        &Vsb[dband * 1024 + voffA[kg]]);
                bf16x4 a1 = *reinterpret_cast<const bf16x4*>(
                        &Vsb[dband * 1024 + voffB[kg]]);
                bf16x8 vf = __builtin_shufflevector(a0, a1, 0, 1, 2, 3, 4, 5, 6, 7);
                oacc[dband] = __builtin_amdgcn_mfma_f32_16x16x32_bf16(
                        vf, pf, oacc[dband], 0, 0, 0);
            }
        }
        __builtin_amdgcn_s_setprio(0);

        // ---- chunk boundary / advance ----
        if (kt == nkt - 1) {
            storeO(chunk);
            if (t < 40) {
                chunk = 31 - pi;
                nkt   = 36 - pi;
                kt = 0;
                mrow = -1e30f; lrow = 0.f;
                #pragma unroll
                for (int dband = 0; dband < 4; ++dband)
                    #pragma unroll
                    for (int r = 0; r < 4; ++r) oacc[dband][r] = 0.f;
                loadQ(chunk);
            }
        } else {
            ++kt;
        }
        buf ^= 1;
        __syncthreads();   // drains vmcnt(0): next tile's staging is complete
    }
}

// ---------------- out projection: (8192 x 768) @ (768 x 768)^T -> f32 ----------------
__global__ __launch_bounds__(256) void k_out_gemm(
        const unsigned short* __restrict__ A, const unsigned short* __restrict__ W,
        float* __restrict__ out) {
    __shared__ __align__(16) unsigned short As[8192];
    __shared__ __align__(16) unsigned short Bs[8192];
    const int tid  = threadIdx.x;
    const int wave = tid >> 6;
    const int lane = tid & 63;
    const int g = lane >> 4, l16 = lane & 15;
    const int m0 = blockIdx.x * 128, n0 = blockIdx.y * 128;
    const int wr = wave >> 1, wc = wave & 1;

    f32x4 acc[4][4] = {};

    for (int k0 = 0; k0 < Cn; k0 += 64) {
        #pragma unroll
        for (int inst = 0; inst < 4; ++inst) {
            const int li = inst * 256 + tid;
            const int row = li >> 3, slot = li & 7;
            const int ch = slot ^ (row & 7);
            ASYNC16(A + (size_t)(m0 + row) * Cn + k0 + ch * 8,
                    &As[(inst * 256 + wave * 64) * 8]);
            ASYNC16(W + (size_t)(n0 + row) * Cn + k0 + ch * 8,
                    &Bs[(inst * 256 + wave * 64) * 8]);
        }
        __syncthreads();
        #pragma unroll
        for (int kk = 0; kk < 2; ++kk) {
            bf16x8 af[4], bfv[4];
            #pragma unroll
            for (int mt = 0; mt < 4; ++mt) {
                const int row = wr * 64 + mt * 16 + l16;
                const int slot = (kk * 4 + g) ^ (row & 7);
                af[mt] = *reinterpret_cast<const bf16x8*>(&As[row * 64 + slot * 8]);
            }
            #pragma unroll
            for (int nt = 0; nt < 4; ++nt) {
                const int row = wc * 64 + nt * 16 + l16;
                const int slot = (kk * 4 + g) ^ (row & 7);
                bfv[nt] = *reinterpret_cast<const bf16x8*>(&Bs[row * 64 + slot * 8]);
            }
            #pragma unroll
            for (int mt = 0; mt < 4; ++mt)
                #pragma unroll
                for (int nt = 0; nt < 4; ++nt)
                    acc[mt][nt] = __builtin_amdgcn_mfma_f32_16x16x32_bf16(
                            af[mt], bfv[nt], acc[mt][nt], 0, 0, 0);
        }
        __syncthreads();
    }

    #pragma unroll
    for (int mt = 0; mt < 4; ++mt)
        #pragma unroll
        for (int nt = 0; nt < 4; ++nt)
            #pragma unroll
            for (int r = 0; r < 4; ++r) {
                const int m = m0 + wr * 64 + mt * 16 + g * 4 + r;
                const int n = n0 + wc * 64 + nt * 16 + l16;
                out[(size_t)m * Cn + n] = acc[mt][nt][r];
            }
}

extern "C" void kernel_launch(void* const* d_in, const int* in_sizes, int n_in,
                              void* d_out, int out_size, void* d_ws, size_t ws_size,
                              hipStream_t stream) {
    const float* x    = (const float*)d_in[0];
    const float* pre  = (const float*)d_in[1];
    const float* wqkv = (const float*)d_in[2];
    const float* wout = (const float*)d_in[3];
    float* out = (float*)d_out;
    char* ws = (char*)d_ws;

    unsigned short* xf  = (unsigned short*)(ws + 0);          // B*TALL*C bf16
    unsigned short* wqb = (unsigned short*)(ws + 14155776);   // 3C*C bf16
    unsigned short* wob = (unsigned short*)(ws + 17694720);   // C*C bf16
    unsigned short* Qb  = (unsigned short*)(ws + 18874368);   // B,H,TALL,HD (pre-scaled)
    unsigned short* Kb  = (unsigned short*)(ws + 33030144);   // B,H,TALL,HD
    unsigned short* Vt  = (unsigned short*)(ws + 47185920);   // B,H,HD,TALL
    unsigned short* Ob  = (unsigned short*)(ws + 61341696);   // B*T,C bf16

    k_build_xfull<<<dim3((Bn * TALLn * Cn / 4) / 256), 256, 0, stream>>>(x, pre, xf);
    k_cast<<<dim3((3 * Cn * Cn / 4) / 256), 256, 0, stream>>>(wqkv, wqb);
    k_cast<<<dim3((Cn * Cn / 4) / 256), 256, 0, stream>>>(wout, wob);
    k_qkv_gemm<<<dim3((Bn * TALLn) / 128, (3 * Cn) / 128), 256, 0, stream>>>(
            xf, wqb, Qb, Kb, Vt);
    k_attn<<<dim3(768), 256, 0, stream>>>(Qb, Kb, Vt, Ob);
    k_out_gemm<<<dim3((Bn * Tn) / 128, Cn / 128), 256, 0, stream>>>(Ob, wob, out);
}